// Round 3
// baseline (2430.761 us; speedup 1.0000x reference)
//
#include <hip/hip_runtime.h>

#define BB 8
#define TT 12
#define NN 10000
#define HH 32
#define EE 320000
#define HOR 12

static __device__ __forceinline__ float sigm(float x) { return 1.0f/(1.0f+__expf(-x)); }
static __device__ __forceinline__ float tanh_fast(float x) { return 1.0f - 2.0f/(1.0f+__expf(2.0f*x)); }
// lane-xor exchange within aligned 4-lane groups (ds_swizzle BitMode, no addr VALU)
static __device__ __forceinline__ float shx1(float v) {
    return __int_as_float(__builtin_amdgcn_ds_swizzle(__float_as_int(v), 0x041F)); // lane^1
}
static __device__ __forceinline__ float shx2(float v) {
    return __int_as_float(__builtin_amdgcn_ds_swizzle(__float_as_int(v), 0x081F)); // lane^2
}

// ---- tiny precompute: A[96] = enc_w . w_ih^T ; W2[160x12] = filt_w @ dec_w ; b2[12]
__global__ void k_prep(const float* __restrict__ enc_w, const float* __restrict__ w_ih,
                       const float* __restrict__ filt_w, const float* __restrict__ filt_b,
                       const float* __restrict__ dec_w, const float* __restrict__ dec_b,
                       float* __restrict__ A, float* __restrict__ W2, float* __restrict__ b2) {
    for (int i = threadIdx.x; i < 96 + 160*12 + 12; i += blockDim.x) {
        if (i < 96) {
            float s = 0.f;
            for (int h = 0; h < HH; h++) s += enc_w[h] * w_ih[i*HH + h];
            A[i] = s;
        } else if (i < 96 + 1920) {
            int j = i - 96; int c = j / 12, o = j % 12;
            float s = 0.f;
            for (int h = 0; h < HH; h++) s += filt_w[c*HH + h] * dec_w[h*12 + o];
            W2[j] = s;
        } else {
            int o = i - 2016;
            float s = dec_b[o];
            for (int h = 0; h < HH; h++) s += filt_b[h] * dec_w[h*12 + o];
            b2[o] = s;
        }
    }
}

// ---- CB[n][96] = b_ih[g] + (g<64 ? b_hh[g] : 0) + sum_h (enc_b[h]+node_emb[n,h]) * w_ih[g,h]
__global__ void k_cb(const float* __restrict__ node_emb, const float* __restrict__ enc_b,
                     const float* __restrict__ w_ih, const float* __restrict__ b_ih,
                     const float* __restrict__ b_hh, float* __restrict__ CB) {
    int id = blockIdx.x * blockDim.x + threadIdx.x;  // N*96 exactly
    int n = id / 96, g = id % 96;
    float s = b_ih[g] + (g < 2*HH ? b_hh[g] : 0.f);
    const float* ne = node_emb + (size_t)n * HH;
    #pragma unroll
    for (int h = 0; h < HH; h++) s += (enc_b[h] + ne[h]) * w_ih[g*HH + h];
    CB[id] = s;
}

// ---- histogram of edge endpoints + weighted degrees
__global__ void k_hist(const int* __restrict__ ei, const float* __restrict__ ew,
                       int* cnt_f, int* cnt_b, float* deg_f, float* deg_b) {
    int e = blockIdx.x * blockDim.x + threadIdx.x;  // EE exactly
    int s = ei[e], t = ei[EE + e];
    float w = ew[e];
    atomicAdd(&cnt_f[t], 1); atomicAdd(&deg_f[t], w);
    atomicAdd(&cnt_b[s], 1); atomicAdd(&deg_b[s], w);
}

// ---- single-block exclusive scan (2 blocks: fwd / bwd) + inv-degree
__global__ void k_scan(const int* __restrict__ cnt_f, const float* __restrict__ deg_f,
                       int* off_f, int* cur_f, float* inv_f,
                       const int* __restrict__ cnt_b, const float* __restrict__ deg_b,
                       int* off_b, int* cur_b, float* inv_b) {
    const int* cnt; const float* deg; int* off; int* cur; float* inv;
    if (blockIdx.x == 0) { cnt = cnt_f; deg = deg_f; off = off_f; cur = cur_f; inv = inv_f; }
    else                 { cnt = cnt_b; deg = deg_b; off = off_b; cur = cur_b; inv = inv_b; }
    __shared__ int part[1024];
    int t = threadIdx.x;
    const int CH = (NN + 1023) / 1024;  // 10
    int beg = t * CH, end = min(beg + CH, NN);
    int s = 0;
    for (int i = beg; i < end; i++) s += cnt[i];
    part[t] = s;
    __syncthreads();
    for (int d = 1; d < 1024; d <<= 1) {
        int add = (t >= d) ? part[t - d] : 0;
        __syncthreads();
        part[t] += add;
        __syncthreads();
    }
    int run = part[t] - s;  // exclusive base
    for (int i = beg; i < end; i++) {
        off[i] = run; cur[i] = run; run += cnt[i];
        float dv = deg[i];
        inv[i] = dv > 0.f ? 1.0f / dv : 1.0f;
    }
    if (t == 1023) off[NN] = part[1023];
}

// ---- scatter edges into CSR buckets
__global__ void k_fill(const int* __restrict__ ei, const float* __restrict__ ew,
                       int* cur_f, int* csr_f_idx, float* csr_f_w,
                       int* cur_b, int* csr_b_idx, float* csr_b_w) {
    int e = blockIdx.x * blockDim.x + threadIdx.x;  // EE exactly
    int s = ei[e], t = ei[EE + e]; float w = ew[e];
    int pf = atomicAdd(&cur_f[t], 1); csr_f_idx[pf] = s; csr_f_w[pf] = w;
    int pb = atomicAdd(&cur_b[s], 1); csr_b_idx[pb] = t; csr_b_w[pb] = w;
}

// ---- fused GRU over T=12, 4-way j-split
// 4 threads per (b,n) row; thread jg owns j = jg*8..jg*8+7. Block 256 thr = 64 rows.
// Grid 1250 blocks -> 5000 waves (~4.9/SIMD). w_hh+A staged in LDS (ds_read_b128,
// immediate offsets, broadcast). h exchange via 2 ds_swizzle xor rounds, no barriers.
// own[8] keeps per-thread state so all register indices are compile-time.
__global__ __launch_bounds__(256) void k_gru(const float* __restrict__ x,
                      const float* __restrict__ CB, const float* __restrict__ Ag,
                      const float* __restrict__ w_hh, const float* __restrict__ b_hh,
                      float* __restrict__ hout) {
    __shared__ float sw[96*32 + 96];
    int tid = threadIdx.x;
    for (int i = tid; i < 96*32; i += 256) sw[i] = w_hh[i];
    if (tid < 96) sw[96*32 + tid] = Ag[tid];
    __syncthreads();

    const int jg = tid & 3, row_local = tid >> 2;
    const int j0 = jg << 3;
    int r = blockIdx.x * 64 + row_local;     // 1250*64 = 80000 exactly
    int b = r / NN, n = r - b * NN;

    float cbR[8], cbZ[8], cbN[8], bn[8];
    {
        const float* cbp = CB + (size_t)n * 96 + j0;
        #pragma unroll
        for (int h = 0; h < 2; h++) {
            float4 v0 = *(const float4*)(cbp + 4*h);
            float4 v1 = *(const float4*)(cbp + 32 + 4*h);
            float4 v2 = *(const float4*)(cbp + 64 + 4*h);
            float4 v3 = *(const float4*)(b_hh + 64 + j0 + 4*h);
            cbR[4*h+0]=v0.x; cbR[4*h+1]=v0.y; cbR[4*h+2]=v0.z; cbR[4*h+3]=v0.w;
            cbZ[4*h+0]=v1.x; cbZ[4*h+1]=v1.y; cbZ[4*h+2]=v1.z; cbZ[4*h+3]=v1.w;
            cbN[4*h+0]=v2.x; cbN[4*h+1]=v2.y; cbN[4*h+2]=v2.z; cbN[4*h+3]=v2.w;
            bn [4*h+0]=v3.x; bn [4*h+1]=v3.y; bn [4*h+2]=v3.z; bn [4*h+3]=v3.w;
        }
    }

    float hid[32];
    #pragma unroll
    for (int i = 0; i < 32; i++) hid[i] = 0.f;
    float own[8];
    #pragma unroll
    for (int k = 0; k < 8; k++) own[k] = 0.f;

    const float* xp = x + (size_t)b * TT * NN + n;
    const float* sA = sw + 96*32;

    #pragma unroll 1
    for (int t = 0; t < TT; t++) {
        float xv = xp[(size_t)t * NN];
        #pragma unroll
        for (int k = 0; k < 8; k++) {
            const float* wr = sw + (j0 + k) * 32;   // gate r row; z at +1024, n at +2048 floats
            float gr = 0.f, gz = 0.f, gn = bn[k];
            #pragma unroll
            for (int q = 0; q < 8; q++) {
                float4 w0 = *(const float4*)(wr + 4*q);
                float4 w1 = *(const float4*)(wr + 1024 + 4*q);
                float4 w2 = *(const float4*)(wr + 2048 + 4*q);
                gr = fmaf(hid[4*q+0], w0.x, gr); gr = fmaf(hid[4*q+1], w0.y, gr);
                gr = fmaf(hid[4*q+2], w0.z, gr); gr = fmaf(hid[4*q+3], w0.w, gr);
                gz = fmaf(hid[4*q+0], w1.x, gz); gz = fmaf(hid[4*q+1], w1.y, gz);
                gz = fmaf(hid[4*q+2], w1.z, gz); gz = fmaf(hid[4*q+3], w1.w, gz);
                gn = fmaf(hid[4*q+0], w2.x, gn); gn = fmaf(hid[4*q+1], w2.y, gn);
                gn = fmaf(hid[4*q+2], w2.z, gn); gn = fmaf(hid[4*q+3], w2.w, gn);
            }
            float rr = sigm(fmaf(xv, sA[j0 + k],      cbR[k]) + gr);
            float zz = sigm(fmaf(xv, sA[32 + j0 + k], cbZ[k]) + gz);
            float nv = tanh_fast(fmaf(xv, sA[64 + j0 + k], cbN[k]) + rr * gn);
            own[k] = (1.f - zz) * nv + zz * own[k];
        }
        if (t < TT - 1) {
            // rebuild full hid[32] from the 4 lanes' own[8]
            float p8[8];
            #pragma unroll
            for (int k = 0; k < 8; k++) p8[k] = shx1(own[k]);
            bool o1 = (jg & 1);
            float lo[8], hi[8];
            #pragma unroll
            for (int k = 0; k < 8; k++) {
                lo[k] = o1 ? p8[k] : own[k];   // j = pairbase + k
                hi[k] = o1 ? own[k] : p8[k];   // j = pairbase + 8 + k
            }
            float plo[8], phi[8];
            #pragma unroll
            for (int k = 0; k < 8; k++) { plo[k] = shx2(lo[k]); phi[k] = shx2(hi[k]); }
            bool o2 = (jg & 2);
            #pragma unroll
            for (int k = 0; k < 8; k++) {
                hid[k]      = o2 ? plo[k] : lo[k];
                hid[8 + k]  = o2 ? phi[k] : hi[k];
                hid[16 + k] = o2 ? lo[k]  : plo[k];
                hid[24 + k] = o2 ? hi[k]  : phi[k];
            }
        }
    }
    float* op = hout + ((size_t)b * NN + n) * HH + j0;
    float4 s0, s1;
    s0.x = own[0]; s0.y = own[1]; s0.z = own[2]; s0.w = own[3];
    s1.x = own[4]; s1.y = own[5]; s1.z = own[6]; s1.w = own[7];
    *(float4*)(op)     = s0;
    *(float4*)(op + 4) = s1;
}

// ---- one diffusion hop: y[b,n,:] = inv_deg[n] * sum_e w[e]*x[b,idx[e],:]
__global__ void k_prop(const float* __restrict__ xin, float* __restrict__ yout,
                       const int* __restrict__ off, const int* __restrict__ idx,
                       const float* __restrict__ w, const float* __restrict__ invdeg) {
    int lane = threadIdx.x & 31;
    int grp  = threadIdx.x >> 5;
    int n = blockIdx.x * 8 + grp;   // NN/8 = 1250 blocks exactly
    int b = blockIdx.y;
    int e0 = off[n], e1 = off[n + 1];
    const float* xb = xin + (size_t)b * NN * HH;
    float acc = 0.f;
    int e = e0;
    for (; e + 4 <= e1; e += 4) {
        int   s0 = idx[e],   s1 = idx[e+1], s2 = idx[e+2], s3 = idx[e+3];
        float w0 = w[e],     w1 = w[e+1],   w2 = w[e+2],   w3 = w[e+3];
        acc += w0 * xb[(size_t)s0*HH + lane];
        acc += w1 * xb[(size_t)s1*HH + lane];
        acc += w2 * xb[(size_t)s2*HH + lane];
        acc += w3 * xb[(size_t)s3*HH + lane];
    }
    for (; e < e1; ++e) acc += w[e] * xb[(size_t)idx[e]*HH + lane];
    yout[((size_t)b*NN + n)*HH + lane] = acc * invdeg[n];
}

// ---- acc[b,n,0:12] += piece[b,n,0:32] @ W2[c0:c0+32, 0:12]
__global__ __launch_bounds__(320) void k_accum(const float* __restrict__ piece,
                        const float* __restrict__ W2, float* __restrict__ acc, int c0) {
    int r = blockIdx.x * blockDim.x + threadIdx.x;  // 80000 exactly
    float a[12];
    float* ap = acc + (size_t)r * 12;
    #pragma unroll
    for (int o = 0; o < 12; o++) a[o] = ap[o];
    const float4* p4 = (const float4*)(piece + (size_t)r * HH);
    #pragma unroll
    for (int q = 0; q < 8; q++) {
        float4 v = p4[q];
        float pv[4] = {v.x, v.y, v.z, v.w};
        #pragma unroll
        for (int k = 0; k < 4; k++) {
            const float* wrow = W2 + (size_t)(c0 + 4*q + k) * 12;
            #pragma unroll
            for (int o = 0; o < 12; o++) a[o] += pv[k] * wrow[o];
        }
    }
    #pragma unroll
    for (int o = 0; o < 12; o++) ap[o] = a[o];
}

// ---- out[b,t,n,0] = acc[b,n,t] + b2[t]
__global__ __launch_bounds__(320) void k_out(const float* __restrict__ acc,
                     const float* __restrict__ b2, float* __restrict__ out) {
    int r = blockIdx.x * blockDim.x + threadIdx.x;  // 80000 exactly
    int b = r / NN, n = r % NN;
    const float* ap = acc + (size_t)r * 12;
    #pragma unroll
    for (int t = 0; t < HOR; t++)
        out[((size_t)(b*HOR + t))*NN + n] = ap[t] + b2[t];
}

extern "C" void kernel_launch(void* const* d_in, const int* in_sizes, int n_in,
                              void* d_out, int out_size, void* d_ws, size_t ws_size,
                              hipStream_t stream) {
    const float* x      = (const float*)d_in[0];
    const int*   ei     = (const int*)d_in[1];
    const float* ew     = (const float*)d_in[2];
    const float* enc_w  = (const float*)d_in[3];
    const float* enc_b  = (const float*)d_in[4];
    const float* nemb   = (const float*)d_in[5];
    const float* w_ih   = (const float*)d_in[6];
    const float* w_hh   = (const float*)d_in[7];
    const float* b_ih   = (const float*)d_in[8];
    const float* b_hh   = (const float*)d_in[9];
    const float* filt_w = (const float*)d_in[10];
    const float* filt_b = (const float*)d_in[11];
    const float* dec_w  = (const float*)d_in[12];
    const float* dec_b  = (const float*)d_in[13];
    float* out = (float*)d_out;

    char* p = (char*)d_ws;
    auto alloc = [&](size_t bytes) -> char* {
        char* q = p; p += (bytes + 255) & ~(size_t)255; return q;
    };
    // zero-region (single memset): acc, cnt_f, cnt_b, deg_f, deg_b
    char* zero_base = p;
    float* acc   = (float*)alloc((size_t)BB*NN*12*4);
    int*   cnt_f = (int*)  alloc((size_t)NN*4);
    int*   cnt_b = (int*)  alloc((size_t)NN*4);
    float* deg_f = (float*)alloc((size_t)NN*4);
    float* deg_b = (float*)alloc((size_t)NN*4);
    size_t zero_bytes = (size_t)(p - zero_base);

    float* h_time = (float*)alloc((size_t)BB*NN*HH*4);
    float* yA     = (float*)alloc((size_t)BB*NN*HH*4);
    float* yB     = (float*)alloc((size_t)BB*NN*HH*4);
    float* CB     = (float*)alloc((size_t)NN*96*4);
    float* A      = (float*)alloc(96*4);
    float* W2     = (float*)alloc(1920*4);
    float* b2     = (float*)alloc(12*4);
    float* inv_f  = (float*)alloc((size_t)NN*4);
    float* inv_b  = (float*)alloc((size_t)NN*4);
    int*   off_f  = (int*)  alloc((size_t)(NN+1)*4);
    int*   off_b  = (int*)  alloc((size_t)(NN+1)*4);
    int*   cur_f  = (int*)  alloc((size_t)NN*4);
    int*   cur_b  = (int*)  alloc((size_t)NN*4);
    int*   cfi    = (int*)  alloc((size_t)EE*4);
    float* cfw    = (float*)alloc((size_t)EE*4);
    int*   cbi    = (int*)  alloc((size_t)EE*4);
    float* cbw    = (float*)alloc((size_t)EE*4);

    hipMemsetAsync(zero_base, 0, zero_bytes, stream);

    k_prep<<<1, 256, 0, stream>>>(enc_w, w_ih, filt_w, filt_b, dec_w, dec_b, A, W2, b2);
    k_cb<<<NN*96/256, 256, 0, stream>>>(nemb, enc_b, w_ih, b_ih, b_hh, CB);
    k_hist<<<EE/256, 256, 0, stream>>>(ei, ew, cnt_f, cnt_b, deg_f, deg_b);
    k_scan<<<2, 1024, 0, stream>>>(cnt_f, deg_f, off_f, cur_f, inv_f,
                                   cnt_b, deg_b, off_b, cur_b, inv_b);
    k_fill<<<EE/256, 256, 0, stream>>>(ei, ew, cur_f, cfi, cfw, cur_b, cbi, cbw);

    k_gru<<<1250, 256, 0, stream>>>(x, CB, A, w_hh, b_hh, h_time);

    dim3 pgrid(NN/8, BB);
    k_accum<<<BB*NN/320, 320, 0, stream>>>(h_time, W2, acc, 0);
    k_prop<<<pgrid, 256, 0, stream>>>(h_time, yA, off_f, cfi, cfw, inv_f);
    k_accum<<<BB*NN/320, 320, 0, stream>>>(yA, W2, acc, 32);
    k_prop<<<pgrid, 256, 0, stream>>>(yA, yB, off_f, cfi, cfw, inv_f);
    k_accum<<<BB*NN/320, 320, 0, stream>>>(yB, W2, acc, 64);
    k_prop<<<pgrid, 256, 0, stream>>>(h_time, yA, off_b, cbi, cbw, inv_b);
    k_accum<<<BB*NN/320, 320, 0, stream>>>(yA, W2, acc, 96);
    k_prop<<<pgrid, 256, 0, stream>>>(yA, yB, off_b, cbi, cbw, inv_b);
    k_accum<<<BB*NN/320, 320, 0, stream>>>(yB, W2, acc, 128);

    k_out<<<BB*NN/320, 320, 0, stream>>>(acc, b2, out);
}

// Round 4
// 455.210 us; speedup vs baseline: 5.3399x; 5.3399x over previous
//
#include <hip/hip_runtime.h>

#define BB 8
#define TT 12
#define NN 10000
#define HH 32
#define EE 320000
#define HOR 12

static __device__ __forceinline__ float sigm(float x) {
    return __builtin_amdgcn_rcpf(1.0f + __expf(-x));
}
static __device__ __forceinline__ float tanh_fast(float x) {
    return 1.0f - 2.0f * __builtin_amdgcn_rcpf(1.0f + __expf(2.0f * x));
}

// ---- tiny precompute: A[96] = enc_w . w_ih^T ; W2[160x12] = filt_w @ dec_w ; b2[12]
__global__ void k_prep(const float* __restrict__ enc_w, const float* __restrict__ w_ih,
                       const float* __restrict__ filt_w, const float* __restrict__ filt_b,
                       const float* __restrict__ dec_w, const float* __restrict__ dec_b,
                       float* __restrict__ A, float* __restrict__ W2, float* __restrict__ b2) {
    for (int i = threadIdx.x; i < 96 + 160*12 + 12; i += blockDim.x) {
        if (i < 96) {
            float s = 0.f;
            for (int h = 0; h < HH; h++) s += enc_w[h] * w_ih[i*HH + h];
            A[i] = s;
        } else if (i < 96 + 1920) {
            int j = i - 96; int c = j / 12, o = j % 12;
            float s = 0.f;
            for (int h = 0; h < HH; h++) s += filt_w[c*HH + h] * dec_w[h*12 + o];
            W2[j] = s;
        } else {
            int o = i - 2016;
            float s = dec_b[o];
            for (int h = 0; h < HH; h++) s += filt_b[h] * dec_w[h*12 + o];
            b2[o] = s;
        }
    }
}

// ---- CB[n][96] = b_ih[g] + (g<64 ? b_hh[g] : 0) + sum_h (enc_b[h]+node_emb[n,h]) * w_ih[g,h]
__global__ void k_cb(const float* __restrict__ node_emb, const float* __restrict__ enc_b,
                     const float* __restrict__ w_ih, const float* __restrict__ b_ih,
                     const float* __restrict__ b_hh, float* __restrict__ CB) {
    int id = blockIdx.x * blockDim.x + threadIdx.x;  // N*96 exactly
    int n = id / 96, g = id % 96;
    float s = b_ih[g] + (g < 2*HH ? b_hh[g] : 0.f);
    const float* ne = node_emb + (size_t)n * HH;
    #pragma unroll
    for (int h = 0; h < HH; h++) s += (enc_b[h] + ne[h]) * w_ih[g*HH + h];
    CB[id] = s;
}

// ---- histogram of edge endpoints + weighted degrees
__global__ void k_hist(const int* __restrict__ ei, const float* __restrict__ ew,
                       int* cnt_f, int* cnt_b, float* deg_f, float* deg_b) {
    int e = blockIdx.x * blockDim.x + threadIdx.x;  // EE exactly
    int s = ei[e], t = ei[EE + e];
    float w = ew[e];
    atomicAdd(&cnt_f[t], 1); atomicAdd(&deg_f[t], w);
    atomicAdd(&cnt_b[s], 1); atomicAdd(&deg_b[s], w);
}

// ---- single-block exclusive scan (2 blocks: fwd / bwd) + inv-degree
__global__ void k_scan(const int* __restrict__ cnt_f, const float* __restrict__ deg_f,
                       int* off_f, int* cur_f, float* inv_f,
                       const int* __restrict__ cnt_b, const float* __restrict__ deg_b,
                       int* off_b, int* cur_b, float* inv_b) {
    const int* cnt; const float* deg; int* off; int* cur; float* inv;
    if (blockIdx.x == 0) { cnt = cnt_f; deg = deg_f; off = off_f; cur = cur_f; inv = inv_f; }
    else                 { cnt = cnt_b; deg = deg_b; off = off_b; cur = cur_b; inv = inv_b; }
    __shared__ int part[1024];
    int t = threadIdx.x;
    const int CH = (NN + 1023) / 1024;  // 10
    int beg = t * CH, end = min(beg + CH, NN);
    int s = 0;
    for (int i = beg; i < end; i++) s += cnt[i];
    part[t] = s;
    __syncthreads();
    for (int d = 1; d < 1024; d <<= 1) {
        int add = (t >= d) ? part[t - d] : 0;
        __syncthreads();
        part[t] += add;
        __syncthreads();
    }
    int run = part[t] - s;  // exclusive base
    for (int i = beg; i < end; i++) {
        off[i] = run; cur[i] = run; run += cnt[i];
        float dv = deg[i];
        inv[i] = dv > 0.f ? 1.0f / dv : 1.0f;
    }
    if (t == 1023) off[NN] = part[1023];
}

// ---- scatter edges into CSR buckets
__global__ void k_fill(const int* __restrict__ ei, const float* __restrict__ ew,
                       int* cur_f, int* csr_f_idx, float* csr_f_w,
                       int* cur_b, int* csr_b_idx, float* csr_b_w) {
    int e = blockIdx.x * blockDim.x + threadIdx.x;  // EE exactly
    int s = ei[e], t = ei[EE + e]; float w = ew[e];
    int pf = atomicAdd(&cur_f[t], 1); csr_f_idx[pf] = s; csr_f_w[pf] = w;
    int pb = atomicAdd(&cur_b[s], 1); csr_b_idx[pb] = t; csr_b_w[pb] = w;
}

// ---- fused GRU over T=12, thread = (row, j): weights in REGISTERS, h in LDS
// Block 256 = 8 rows x 32 j-threads; a wave owns 2 complete rows so the h
// exchange is intra-wave: ds_write + s_waitcnt lgkmcnt(0), no per-step barrier.
// 96 weight regs, all indices compile-time. 40000 waves total.
// LDS stride 36 floats: conflict-free writes (banks 4*rl+j) and 16B-aligned rows.
__global__ __launch_bounds__(256) void k_gru(const float* __restrict__ x,
                      const float* __restrict__ CB, const float* __restrict__ Ag,
                      const float* __restrict__ w_hh, const float* __restrict__ b_hh,
                      float* __restrict__ hout) {
    __shared__ float swt[96*36];
    __shared__ float sh[8*36];
    int tid = threadIdx.x;
    for (int i = tid; i < 96*32; i += 256) {
        int g = i >> 5, h = i & 31;
        swt[g*36 + h] = w_hh[i];
    }
    __syncthreads();

    const int j = tid & 31, rl = tid >> 5;
    int r = blockIdx.x * 8 + rl;              // grid 10000 -> 80000 exactly
    int b = r / NN, n = r - b * NN;

    float wr_[32], wz_[32], wn_[32];
    #pragma unroll
    for (int q = 0; q < 8; q++) {
        float4 v0 = *(const float4*)(swt + j*36        + 4*q);
        float4 v1 = *(const float4*)(swt + (32+j)*36   + 4*q);
        float4 v2 = *(const float4*)(swt + (64+j)*36   + 4*q);
        wr_[4*q+0]=v0.x; wr_[4*q+1]=v0.y; wr_[4*q+2]=v0.z; wr_[4*q+3]=v0.w;
        wz_[4*q+0]=v1.x; wz_[4*q+1]=v1.y; wz_[4*q+2]=v1.z; wz_[4*q+3]=v1.w;
        wn_[4*q+0]=v2.x; wn_[4*q+1]=v2.y; wn_[4*q+2]=v2.z; wn_[4*q+3]=v2.w;
    }
    const float* cbp = CB + (size_t)n * 96;
    float cbR = cbp[j], cbZ = cbp[32+j], cbN = cbp[64+j];
    float bn0 = b_hh[64+j];
    float aR = Ag[j], aZ = Ag[32+j], aN = Ag[64+j];

    float xv[12];
    const float* xp = x + (size_t)b * TT * NN + n;
    #pragma unroll
    for (int t = 0; t < TT; t++) xv[t] = xp[(size_t)t * NN];

    float* shrow = sh + rl*36;
    // t = 0 (h=0 -> gh=0)
    float own;
    {
        float rr = sigm(fmaf(xv[0], aR, cbR));
        float zz = sigm(fmaf(xv[0], aZ, cbZ));
        float nv = tanh_fast(fmaf(xv[0], aN, cbN) + rr * bn0);
        own = (1.f - zz) * nv;
    }
    shrow[j] = own;

    #pragma unroll 1
    for (int t = 1; t < TT; t++) {
        asm volatile("s_waitcnt lgkmcnt(0)" ::: "memory");
        float hid[32];
        #pragma unroll
        for (int q = 0; q < 8; q++) {
            float4 v = *(const float4*)(shrow + 4*q);
            hid[4*q]=v.x; hid[4*q+1]=v.y; hid[4*q+2]=v.z; hid[4*q+3]=v.w;
        }
        float gr = 0.f, gz = 0.f, gn = bn0;
        #pragma unroll
        for (int h = 0; h < 32; h++) {
            gr = fmaf(hid[h], wr_[h], gr);
            gz = fmaf(hid[h], wz_[h], gz);
            gn = fmaf(hid[h], wn_[h], gn);
        }
        float rr = sigm(fmaf(xv[t], aR, cbR) + gr);
        float zz = sigm(fmaf(xv[t], aZ, cbZ) + gz);
        float nv = tanh_fast(fmaf(xv[t], aN, cbN) + rr * gn);
        own = (1.f - zz) * nv + zz * own;
        if (t < TT-1) shrow[j] = own;
    }
    hout[((size_t)b * NN + n) * HH + j] = own;
}

// ---- one diffusion hop: y[b,n,:] = inv_deg[n] * sum_e w[e]*x[b,idx[e],:]
__global__ void k_prop(const float* __restrict__ xin, float* __restrict__ yout,
                       const int* __restrict__ off, const int* __restrict__ idx,
                       const float* __restrict__ w, const float* __restrict__ invdeg) {
    int lane = threadIdx.x & 31;
    int grp  = threadIdx.x >> 5;
    int n = blockIdx.x * 8 + grp;   // NN/8 = 1250 blocks exactly
    int b = blockIdx.y;
    int e0 = off[n], e1 = off[n + 1];
    const float* xb = xin + (size_t)b * NN * HH;
    float acc = 0.f;
    int e = e0;
    for (; e + 4 <= e1; e += 4) {
        int   s0 = idx[e],   s1 = idx[e+1], s2 = idx[e+2], s3 = idx[e+3];
        float w0 = w[e],     w1 = w[e+1],   w2 = w[e+2],   w3 = w[e+3];
        acc += w0 * xb[(size_t)s0*HH + lane];
        acc += w1 * xb[(size_t)s1*HH + lane];
        acc += w2 * xb[(size_t)s2*HH + lane];
        acc += w3 * xb[(size_t)s3*HH + lane];
    }
    for (; e < e1; ++e) acc += w[e] * xb[(size_t)idx[e]*HH + lane];
    yout[((size_t)b*NN + n)*HH + lane] = acc * invdeg[n];
}

// ---- fused decoder: out[b,t,n] = b2[t] + sum_{pi,c} piece_pi[b,n,c] * W2[pi*32+c, t]
__global__ __launch_bounds__(256) void k_dec(const float* __restrict__ p0,
                     const float* __restrict__ p1, const float* __restrict__ p2,
                     const float* __restrict__ p3, const float* __restrict__ p4,
                     const float* __restrict__ W2, const float* __restrict__ b2,
                     float* __restrict__ out) {
    __shared__ float sW[1920];
    __shared__ float sb[12];
    int tid = threadIdx.x;
    for (int i = tid; i < 1920; i += 256) sW[i] = W2[i];
    if (tid < 12) sb[tid] = b2[tid];
    __syncthreads();
    int r = blockIdx.x * 256 + tid;
    if (r >= BB*NN) return;
    int b = r / NN, n = r - b*NN;
    float a[12];
    #pragma unroll
    for (int o = 0; o < 12; o++) a[o] = sb[o];
    const float* ps[5] = {p0, p1, p2, p3, p4};
    #pragma unroll
    for (int pi = 0; pi < 5; pi++) {
        const float4* pp = (const float4*)(ps[pi] + (size_t)r * HH);
        #pragma unroll
        for (int q = 0; q < 8; q++) {
            float4 v = pp[q];
            float pv[4] = {v.x, v.y, v.z, v.w};
            #pragma unroll
            for (int k = 0; k < 4; k++) {
                const float* wrow = sW + (pi*32 + 4*q + k) * 12;
                #pragma unroll
                for (int o = 0; o < 12; o++) a[o] = fmaf(pv[k], wrow[o], a[o]);
            }
        }
    }
    #pragma unroll
    for (int t = 0; t < HOR; t++)
        out[((size_t)(b*HOR + t))*NN + n] = a[t];
}

extern "C" void kernel_launch(void* const* d_in, const int* in_sizes, int n_in,
                              void* d_out, int out_size, void* d_ws, size_t ws_size,
                              hipStream_t stream) {
    const float* x      = (const float*)d_in[0];
    const int*   ei     = (const int*)d_in[1];
    const float* ew     = (const float*)d_in[2];
    const float* enc_w  = (const float*)d_in[3];
    const float* enc_b  = (const float*)d_in[4];
    const float* nemb   = (const float*)d_in[5];
    const float* w_ih   = (const float*)d_in[6];
    const float* w_hh   = (const float*)d_in[7];
    const float* b_ih   = (const float*)d_in[8];
    const float* b_hh   = (const float*)d_in[9];
    const float* filt_w = (const float*)d_in[10];
    const float* filt_b = (const float*)d_in[11];
    const float* dec_w  = (const float*)d_in[12];
    const float* dec_b  = (const float*)d_in[13];
    float* out = (float*)d_out;

    char* p = (char*)d_ws;
    auto alloc = [&](size_t bytes) -> char* {
        char* q = p; p += (bytes + 255) & ~(size_t)255; return q;
    };
    // zero-region (single memset): cnt_f, cnt_b, deg_f, deg_b
    char* zero_base = p;
    int*   cnt_f = (int*)  alloc((size_t)NN*4);
    int*   cnt_b = (int*)  alloc((size_t)NN*4);
    float* deg_f = (float*)alloc((size_t)NN*4);
    float* deg_b = (float*)alloc((size_t)NN*4);
    size_t zero_bytes = (size_t)(p - zero_base);

    float* h_time = (float*)alloc((size_t)BB*NN*HH*4);
    float* yA     = (float*)alloc((size_t)BB*NN*HH*4);
    float* yB     = (float*)alloc((size_t)BB*NN*HH*4);
    float* yC     = (float*)alloc((size_t)BB*NN*HH*4);
    float* yD     = (float*)alloc((size_t)BB*NN*HH*4);
    float* CB     = (float*)alloc((size_t)NN*96*4);
    float* A      = (float*)alloc(96*4);
    float* W2     = (float*)alloc(1920*4);
    float* b2     = (float*)alloc(12*4);
    float* inv_f  = (float*)alloc((size_t)NN*4);
    float* inv_b  = (float*)alloc((size_t)NN*4);
    int*   off_f  = (int*)  alloc((size_t)(NN+1)*4);
    int*   off_b  = (int*)  alloc((size_t)(NN+1)*4);
    int*   cur_f  = (int*)  alloc((size_t)NN*4);
    int*   cur_b  = (int*)  alloc((size_t)NN*4);
    int*   cfi    = (int*)  alloc((size_t)EE*4);
    float* cfw    = (float*)alloc((size_t)EE*4);
    int*   cbi    = (int*)  alloc((size_t)EE*4);
    float* cbw    = (float*)alloc((size_t)EE*4);

    hipMemsetAsync(zero_base, 0, zero_bytes, stream);

    k_prep<<<1, 256, 0, stream>>>(enc_w, w_ih, filt_w, filt_b, dec_w, dec_b, A, W2, b2);
    k_cb<<<NN*96/256, 256, 0, stream>>>(nemb, enc_b, w_ih, b_ih, b_hh, CB);
    k_hist<<<EE/256, 256, 0, stream>>>(ei, ew, cnt_f, cnt_b, deg_f, deg_b);
    k_scan<<<2, 1024, 0, stream>>>(cnt_f, deg_f, off_f, cur_f, inv_f,
                                   cnt_b, deg_b, off_b, cur_b, inv_b);
    k_fill<<<EE/256, 256, 0, stream>>>(ei, ew, cur_f, cfi, cfw, cur_b, cbi, cbw);

    k_gru<<<10000, 256, 0, stream>>>(x, CB, A, w_hh, b_hh, h_time);

    dim3 pgrid(NN/8, BB);
    k_prop<<<pgrid, 256, 0, stream>>>(h_time, yA, off_f, cfi, cfw, inv_f);
    k_prop<<<pgrid, 256, 0, stream>>>(yA, yB, off_f, cfi, cfw, inv_f);
    k_prop<<<pgrid, 256, 0, stream>>>(h_time, yC, off_b, cbi, cbw, inv_b);
    k_prop<<<pgrid, 256, 0, stream>>>(yC, yD, off_b, cbi, cbw, inv_b);

    k_dec<<<(BB*NN + 255)/256, 256, 0, stream>>>(h_time, yA, yB, yC, yD, W2, b2, out);
}

// Round 5
// 419.587 us; speedup vs baseline: 5.7932x; 1.0849x over previous
//
#include <hip/hip_runtime.h>

#define BB 8
#define TT 12
#define NN 10000
#define HH 32
#define EE 320000
#define HOR 12

static __device__ __forceinline__ float sigm(float x) {
    return __builtin_amdgcn_rcpf(1.0f + __expf(-x));
}
static __device__ __forceinline__ float tanh_fast(float x) {
    return 1.0f - 2.0f * __builtin_amdgcn_rcpf(1.0f + __expf(2.0f * x));
}

// ---- tiny precompute: A[96] = enc_w . w_ih^T ; W2[160x12] = filt_w @ dec_w ; b2[12]
__global__ void k_prep(const float* __restrict__ enc_w, const float* __restrict__ w_ih,
                       const float* __restrict__ filt_w, const float* __restrict__ filt_b,
                       const float* __restrict__ dec_w, const float* __restrict__ dec_b,
                       float* __restrict__ A, float* __restrict__ W2, float* __restrict__ b2) {
    for (int i = threadIdx.x; i < 96 + 160*12 + 12; i += blockDim.x) {
        if (i < 96) {
            float s = 0.f;
            for (int h = 0; h < HH; h++) s += enc_w[h] * w_ih[i*HH + h];
            A[i] = s;
        } else if (i < 96 + 1920) {
            int j = i - 96; int c = j / 12, o = j % 12;
            float s = 0.f;
            for (int h = 0; h < HH; h++) s += filt_w[c*HH + h] * dec_w[h*12 + o];
            W2[j] = s;
        } else {
            int o = i - 2016;
            float s = dec_b[o];
            for (int h = 0; h < HH; h++) s += filt_b[h] * dec_w[h*12 + o];
            b2[o] = s;
        }
    }
}

// ---- CB[n][96] = b_ih[g] + (g<64 ? b_hh[g] : 0) + sum_h (enc_b[h]+node_emb[n,h]) * w_ih[g,h]
__global__ void k_cb(const float* __restrict__ node_emb, const float* __restrict__ enc_b,
                     const float* __restrict__ w_ih, const float* __restrict__ b_ih,
                     const float* __restrict__ b_hh, float* __restrict__ CB) {
    int id = blockIdx.x * blockDim.x + threadIdx.x;  // N*96 exactly
    int n = id / 96, g = id % 96;
    float s = b_ih[g] + (g < 2*HH ? b_hh[g] : 0.f);
    const float* ne = node_emb + (size_t)n * HH;
    #pragma unroll
    for (int h = 0; h < HH; h++) s += (enc_b[h] + ne[h]) * w_ih[g*HH + h];
    CB[id] = s;
}

// ---- histogram of edge endpoints + weighted degrees
__global__ void k_hist(const int* __restrict__ ei, const float* __restrict__ ew,
                       int* cnt_f, int* cnt_b, float* deg_f, float* deg_b) {
    int e = blockIdx.x * blockDim.x + threadIdx.x;  // EE exactly
    int s = ei[e], t = ei[EE + e];
    float w = ew[e];
    atomicAdd(&cnt_f[t], 1); atomicAdd(&deg_f[t], w);
    atomicAdd(&cnt_b[s], 1); atomicAdd(&deg_b[s], w);
}

// ---- single-block exclusive scan (2 blocks: fwd / bwd) + inv-degree
__global__ void k_scan(const int* __restrict__ cnt_f, const float* __restrict__ deg_f,
                       int* off_f, int* cur_f, float* inv_f,
                       const int* __restrict__ cnt_b, const float* __restrict__ deg_b,
                       int* off_b, int* cur_b, float* inv_b) {
    const int* cnt; const float* deg; int* off; int* cur; float* inv;
    if (blockIdx.x == 0) { cnt = cnt_f; deg = deg_f; off = off_f; cur = cur_f; inv = inv_f; }
    else                 { cnt = cnt_b; deg = deg_b; off = off_b; cur = cur_b; inv = inv_b; }
    __shared__ int part[1024];
    int t = threadIdx.x;
    const int CH = (NN + 1023) / 1024;  // 10
    int beg = t * CH, end = min(beg + CH, NN);
    int s = 0;
    for (int i = beg; i < end; i++) s += cnt[i];
    part[t] = s;
    __syncthreads();
    for (int d = 1; d < 1024; d <<= 1) {
        int add = (t >= d) ? part[t - d] : 0;
        __syncthreads();
        part[t] += add;
        __syncthreads();
    }
    int run = part[t] - s;  // exclusive base
    for (int i = beg; i < end; i++) {
        off[i] = run; cur[i] = run; run += cnt[i];
        float dv = deg[i];
        inv[i] = dv > 0.f ? 1.0f / dv : 1.0f;
    }
    if (t == 1023) off[NN] = part[1023];
}

// ---- scatter edges into CSR buckets; weights pre-scaled by inv-degree
__global__ void k_fill(const int* __restrict__ ei, const float* __restrict__ ew,
                       const float* __restrict__ inv_f, const float* __restrict__ inv_b,
                       int* cur_f, int* csr_f_idx, float* csr_f_w,
                       int* cur_b, int* csr_b_idx, float* csr_b_w) {
    int e = blockIdx.x * blockDim.x + threadIdx.x;  // EE exactly
    int s = ei[e], t = ei[EE + e]; float w = ew[e];
    int pf = atomicAdd(&cur_f[t], 1); csr_f_idx[pf] = s; csr_f_w[pf] = w * inv_f[t];
    int pb = atomicAdd(&cur_b[s], 1); csr_b_idx[pb] = t; csr_b_w[pb] = w * inv_b[s];
}

// ---- fused GRU over T=12, thread = (2 rows, j): h in LDS, 2-row amortization
// Block 256 = 8 groups x 32 j; group g owns rows r0+g and r0+g+8 (16 rows/block).
// Wave = 2 groups -> owns its 4 rows entirely => intra-wave exchange via
// ds_write + s_waitcnt lgkmcnt(0), no per-step barrier. Output n-major [n][b][h].
__global__ __launch_bounds__(256) void k_gru(const float* __restrict__ x,
                      const float* __restrict__ CB, const float* __restrict__ Ag,
                      const float* __restrict__ w_hh, const float* __restrict__ b_hh,
                      float* __restrict__ hout) {
    __shared__ float swt[96*36];
    __shared__ float sh[16*36];
    int tid = threadIdx.x;
    for (int i = tid; i < 96*32; i += 256) {
        int g = i >> 5, h = i & 31;
        swt[g*36 + h] = w_hh[i];
    }
    __syncthreads();

    const int j = tid & 31, g = tid >> 5;     // g in 0..7
    int r0 = blockIdx.x * 16;                 // 5000 blocks -> 80000 rows
    int rA = r0 + g, rB = r0 + g + 8;
    int bA = rA / NN, nA = rA - bA * NN;
    int bB = rB / NN, nB = rB - bB * NN;

    const float* cA = CB + (size_t)nA * 96;
    const float* cBp = CB + (size_t)nB * 96;
    float cbRA = cA[j],  cbZA = cA[32+j],  cbNA = cA[64+j];
    float cbRB = cBp[j], cbZB = cBp[32+j], cbNB = cBp[64+j];
    float bn0 = b_hh[64+j];
    float aR = Ag[j], aZ = Ag[32+j], aN = Ag[64+j];

    float xA[12], xB[12];
    const float* xpA = x + (size_t)bA * TT * NN + nA;
    const float* xpB = x + (size_t)bB * TT * NN + nB;
    #pragma unroll
    for (int t = 0; t < TT; t++) { xA[t] = xpA[(size_t)t * NN]; xB[t] = xpB[(size_t)t * NN]; }

    float* shA = sh + g * 36;
    float* shB = sh + (g + 8) * 36;

    float ownA, ownB;
    {   // t = 0: h = 0
        float rrA = sigm(fmaf(xA[0], aR, cbRA));
        float zzA = sigm(fmaf(xA[0], aZ, cbZA));
        float nvA = tanh_fast(fmaf(xA[0], aN, cbNA) + rrA * bn0);
        ownA = (1.f - zzA) * nvA;
        float rrB = sigm(fmaf(xB[0], aR, cbRB));
        float zzB = sigm(fmaf(xB[0], aZ, cbZB));
        float nvB = tanh_fast(fmaf(xB[0], aN, cbNB) + rrB * bn0);
        ownB = (1.f - zzB) * nvB;
    }
    shA[j] = ownA;
    shB[j] = ownB;

    #pragma unroll 1
    for (int t = 1; t < TT; t++) {
        asm volatile("s_waitcnt lgkmcnt(0)" ::: "memory");
        float grA = 0.f, gzA = 0.f, gnA = bn0;
        float grB = 0.f, gzB = 0.f, gnB = bn0;
        #pragma unroll
        for (int q = 0; q < 8; q++) {
            float4 hA = *(const float4*)(shA + 4*q);
            float4 hB = *(const float4*)(shB + 4*q);
            float4 w0 = *(const float4*)(swt + j*36      + 4*q);
            float4 w1 = *(const float4*)(swt + (32+j)*36 + 4*q);
            float4 w2 = *(const float4*)(swt + (64+j)*36 + 4*q);
            grA = fmaf(hA.x, w0.x, grA); grA = fmaf(hA.y, w0.y, grA);
            grA = fmaf(hA.z, w0.z, grA); grA = fmaf(hA.w, w0.w, grA);
            gzA = fmaf(hA.x, w1.x, gzA); gzA = fmaf(hA.y, w1.y, gzA);
            gzA = fmaf(hA.z, w1.z, gzA); gzA = fmaf(hA.w, w1.w, gzA);
            gnA = fmaf(hA.x, w2.x, gnA); gnA = fmaf(hA.y, w2.y, gnA);
            gnA = fmaf(hA.z, w2.z, gnA); gnA = fmaf(hA.w, w2.w, gnA);
            grB = fmaf(hB.x, w0.x, grB); grB = fmaf(hB.y, w0.y, grB);
            grB = fmaf(hB.z, w0.z, grB); grB = fmaf(hB.w, w0.w, grB);
            gzB = fmaf(hB.x, w1.x, gzB); gzB = fmaf(hB.y, w1.y, gzB);
            gzB = fmaf(hB.z, w1.z, gzB); gzB = fmaf(hB.w, w1.w, gzB);
            gnB = fmaf(hB.x, w2.x, gnB); gnB = fmaf(hB.y, w2.y, gnB);
            gnB = fmaf(hB.z, w2.z, gnB); gnB = fmaf(hB.w, w2.w, gnB);
        }
        float rrA = sigm(fmaf(xA[t], aR, cbRA) + grA);
        float zzA = sigm(fmaf(xA[t], aZ, cbZA) + gzA);
        float nvA = tanh_fast(fmaf(xA[t], aN, cbNA) + rrA * gnA);
        ownA = (1.f - zzA) * nvA + zzA * ownA;
        float rrB = sigm(fmaf(xB[t], aR, cbRB) + grB);
        float zzB = sigm(fmaf(xB[t], aZ, cbZB) + gzB);
        float nvB = tanh_fast(fmaf(xB[t], aN, cbNB) + rrB * gnB);
        ownB = (1.f - zzB) * nvB + zzB * ownB;
        if (t < TT-1) { shA[j] = ownA; shB[j] = ownB; }
    }
    hout[((size_t)nA * BB + bA) * HH + j] = ownA;
    hout[((size_t)nB * BB + bB) * HH + j] = ownB;
}

// ---- dual-direction diffusion hop, all 8 batches per wave, n-major layout
// wave per node: lane = (bh in 0..1, h in 0..31); per edge: 4 coalesced 256B
// loads at imm offsets (b = bh + 2k), 2-edge unroll -> 8 outstanding loads.
// CSR weights pre-scaled by inv-degree.
__global__ __launch_bounds__(256) void k_prop(
        const float* __restrict__ xF, const float* __restrict__ xB,
        float* __restrict__ yF, float* __restrict__ yB,
        const int* __restrict__ offF, const int* __restrict__ idxF, const float* __restrict__ wF,
        const int* __restrict__ offB, const int* __restrict__ idxB, const float* __restrict__ wB) {
    int wid = threadIdx.x >> 6;         // 0..3
    int l   = threadIdx.x & 63;
    int h = l & 31, bh = l >> 5;        // bh 0..1
    int n = blockIdx.x * 4 + wid;       // 2500 blocks exactly
    int lo = (bh << 5) + h;

    {   // forward
        int e0 = offF[n], e1 = offF[n+1];
        float a0=0.f, a1=0.f, a2=0.f, a3=0.f;
        int e = e0;
        for (; e + 2 <= e1; e += 2) {
            int s0 = idxF[e], s1 = idxF[e+1];
            float w0 = wF[e], w1 = wF[e+1];
            const float* p0 = xF + ((size_t)s0 << 8) + lo;
            const float* p1 = xF + ((size_t)s1 << 8) + lo;
            a0 = fmaf(w0, p0[0],   a0); a1 = fmaf(w0, p0[64],  a1);
            a2 = fmaf(w0, p0[128], a2); a3 = fmaf(w0, p0[192], a3);
            a0 = fmaf(w1, p1[0],   a0); a1 = fmaf(w1, p1[64],  a1);
            a2 = fmaf(w1, p1[128], a2); a3 = fmaf(w1, p1[192], a3);
        }
        if (e < e1) {
            int s0 = idxF[e]; float w0 = wF[e];
            const float* p0 = xF + ((size_t)s0 << 8) + lo;
            a0 = fmaf(w0, p0[0],   a0); a1 = fmaf(w0, p0[64],  a1);
            a2 = fmaf(w0, p0[128], a2); a3 = fmaf(w0, p0[192], a3);
        }
        float* d = yF + ((size_t)n << 8) + lo;
        d[0] = a0; d[64] = a1; d[128] = a2; d[192] = a3;
    }
    {   // backward
        int e0 = offB[n], e1 = offB[n+1];
        float a0=0.f, a1=0.f, a2=0.f, a3=0.f;
        int e = e0;
        for (; e + 2 <= e1; e += 2) {
            int s0 = idxB[e], s1 = idxB[e+1];
            float w0 = wB[e], w1 = wB[e+1];
            const float* p0 = xB + ((size_t)s0 << 8) + lo;
            const float* p1 = xB + ((size_t)s1 << 8) + lo;
            a0 = fmaf(w0, p0[0],   a0); a1 = fmaf(w0, p0[64],  a1);
            a2 = fmaf(w0, p0[128], a2); a3 = fmaf(w0, p0[192], a3);
            a0 = fmaf(w1, p1[0],   a0); a1 = fmaf(w1, p1[64],  a1);
            a2 = fmaf(w1, p1[128], a2); a3 = fmaf(w1, p1[192], a3);
        }
        if (e < e1) {
            int s0 = idxB[e]; float w0 = wB[e];
            const float* p0 = xB + ((size_t)s0 << 8) + lo;
            a0 = fmaf(w0, p0[0],   a0); a1 = fmaf(w0, p0[64],  a1);
            a2 = fmaf(w0, p0[128], a2); a3 = fmaf(w0, p0[192], a3);
        }
        float* d = yB + ((size_t)n << 8) + lo;
        d[0] = a0; d[64] = a1; d[128] = a2; d[192] = a3;
    }
}

// ---- fused decoder: out[b,t,n] = b2[t] + sum_{pi,c} piece_pi[n,b,c] * W2[pi*32+c, t]
__global__ __launch_bounds__(256) void k_dec(const float* __restrict__ p0,
                     const float* __restrict__ p1, const float* __restrict__ p2,
                     const float* __restrict__ p3, const float* __restrict__ p4,
                     const float* __restrict__ W2, const float* __restrict__ b2,
                     float* __restrict__ out) {
    __shared__ float sW[1920];
    __shared__ float sb[12];
    int tid = threadIdx.x;
    for (int i = tid; i < 1920; i += 256) sW[i] = W2[i];
    if (tid < 12) sb[tid] = b2[tid];
    __syncthreads();
    int r = blockIdx.x * 256 + tid;
    if (r >= BB*NN) return;
    int b = r / NN, n = r - b*NN;
    size_t base = ((size_t)n * BB + b) * HH;
    float a[12];
    #pragma unroll
    for (int o = 0; o < 12; o++) a[o] = sb[o];
    const float* ps[5] = {p0, p1, p2, p3, p4};
    #pragma unroll
    for (int pi = 0; pi < 5; pi++) {
        const float4* pp = (const float4*)(ps[pi] + base);
        #pragma unroll
        for (int q = 0; q < 8; q++) {
            float4 v = pp[q];
            float pv[4] = {v.x, v.y, v.z, v.w};
            #pragma unroll
            for (int k = 0; k < 4; k++) {
                const float* wrow = sW + (pi*32 + 4*q + k) * 12;
                #pragma unroll
                for (int o = 0; o < 12; o++) a[o] = fmaf(pv[k], wrow[o], a[o]);
            }
        }
    }
    #pragma unroll
    for (int t = 0; t < HOR; t++)
        out[((size_t)(b*HOR + t))*NN + n] = a[t];
}

extern "C" void kernel_launch(void* const* d_in, const int* in_sizes, int n_in,
                              void* d_out, int out_size, void* d_ws, size_t ws_size,
                              hipStream_t stream) {
    const float* x      = (const float*)d_in[0];
    const int*   ei     = (const int*)d_in[1];
    const float* ew     = (const float*)d_in[2];
    const float* enc_w  = (const float*)d_in[3];
    const float* enc_b  = (const float*)d_in[4];
    const float* nemb   = (const float*)d_in[5];
    const float* w_ih   = (const float*)d_in[6];
    const float* w_hh   = (const float*)d_in[7];
    const float* b_ih   = (const float*)d_in[8];
    const float* b_hh   = (const float*)d_in[9];
    const float* filt_w = (const float*)d_in[10];
    const float* filt_b = (const float*)d_in[11];
    const float* dec_w  = (const float*)d_in[12];
    const float* dec_b  = (const float*)d_in[13];
    float* out = (float*)d_out;

    char* p = (char*)d_ws;
    auto alloc = [&](size_t bytes) -> char* {
        char* q = p; p += (bytes + 255) & ~(size_t)255; return q;
    };
    // zero-region (single memset): cnt_f, cnt_b, deg_f, deg_b
    char* zero_base = p;
    int*   cnt_f = (int*)  alloc((size_t)NN*4);
    int*   cnt_b = (int*)  alloc((size_t)NN*4);
    float* deg_f = (float*)alloc((size_t)NN*4);
    float* deg_b = (float*)alloc((size_t)NN*4);
    size_t zero_bytes = (size_t)(p - zero_base);

    float* h_time = (float*)alloc((size_t)BB*NN*HH*4);
    float* yA     = (float*)alloc((size_t)BB*NN*HH*4);
    float* yB     = (float*)alloc((size_t)BB*NN*HH*4);
    float* yC     = (float*)alloc((size_t)BB*NN*HH*4);
    float* yD     = (float*)alloc((size_t)BB*NN*HH*4);
    float* CB     = (float*)alloc((size_t)NN*96*4);
    float* A      = (float*)alloc(96*4);
    float* W2     = (float*)alloc(1920*4);
    float* b2     = (float*)alloc(12*4);
    float* inv_f  = (float*)alloc((size_t)NN*4);
    float* inv_b  = (float*)alloc((size_t)NN*4);
    int*   off_f  = (int*)  alloc((size_t)(NN+1)*4);
    int*   off_b  = (int*)  alloc((size_t)(NN+1)*4);
    int*   cur_f  = (int*)  alloc((size_t)NN*4);
    int*   cur_b  = (int*)  alloc((size_t)NN*4);
    int*   cfi    = (int*)  alloc((size_t)EE*4);
    float* cfw    = (float*)alloc((size_t)EE*4);
    int*   cbi    = (int*)  alloc((size_t)EE*4);
    float* cbw    = (float*)alloc((size_t)EE*4);

    hipMemsetAsync(zero_base, 0, zero_bytes, stream);

    k_prep<<<1, 256, 0, stream>>>(enc_w, w_ih, filt_w, filt_b, dec_w, dec_b, A, W2, b2);
    k_cb<<<NN*96/256, 256, 0, stream>>>(nemb, enc_b, w_ih, b_ih, b_hh, CB);
    k_hist<<<EE/256, 256, 0, stream>>>(ei, ew, cnt_f, cnt_b, deg_f, deg_b);
    k_scan<<<2, 1024, 0, stream>>>(cnt_f, deg_f, off_f, cur_f, inv_f,
                                   cnt_b, deg_b, off_b, cur_b, inv_b);
    k_fill<<<EE/256, 256, 0, stream>>>(ei, ew, inv_f, inv_b,
                                       cur_f, cfi, cfw, cur_b, cbi, cbw);

    k_gru<<<5000, 256, 0, stream>>>(x, CB, A, w_hh, b_hh, h_time);

    k_prop<<<2500, 256, 0, stream>>>(h_time, h_time, yA, yC,
                                     off_f, cfi, cfw, off_b, cbi, cbw);
    k_prop<<<2500, 256, 0, stream>>>(yA, yC, yB, yD,
                                     off_f, cfi, cfw, off_b, cbi, cbw);

    k_dec<<<(BB*NN + 255)/256, 256, 0, stream>>>(h_time, yA, yB, yC, yD, W2, b2, out);
}

// Round 6
// 344.579 us; speedup vs baseline: 7.0543x; 1.2177x over previous
//
#include <hip/hip_runtime.h>
#include <hip/hip_fp16.h>

#define BB 8
#define TT 12
#define NN 10000
#define HH 32
#define EE 320000
#define HOR 12

static __device__ __forceinline__ float sigm(float x) {
    return __builtin_amdgcn_rcpf(1.0f + __expf(-x));
}
static __device__ __forceinline__ float tanh_fast(float x) {
    return 1.0f - 2.0f * __builtin_amdgcn_rcpf(1.0f + __expf(2.0f * x));
}
static __device__ __forceinline__ float2 uph2(unsigned u) {
    __half2 h = *(__half2*)&u;
    return __half22float2(h);
}
static __device__ __forceinline__ unsigned pkh2(float a, float b) {
    __half2 h = __floats2half2_rn(a, b);
    return *(unsigned*)&h;
}

// ---- CB[n][96] = b_ih[g] + (g<64 ? b_hh[g] : 0) + sum_h (enc_b[h]+node_emb[n,h]) * w_ih[g,h]
// Last block additionally computes A[96] = enc_w . w_ih^T ; W2 = filt_w@dec_w ; b2.
__global__ void k_cb(const float* __restrict__ node_emb, const float* __restrict__ enc_b,
                     const float* __restrict__ w_ih, const float* __restrict__ b_ih,
                     const float* __restrict__ b_hh,
                     const float* __restrict__ enc_w, const float* __restrict__ filt_w,
                     const float* __restrict__ filt_b, const float* __restrict__ dec_w,
                     const float* __restrict__ dec_b,
                     float* __restrict__ CB, float* __restrict__ A,
                     float* __restrict__ W2, float* __restrict__ b2) {
    if (blockIdx.x == NN*96/256) {   // prep block
        for (int i = threadIdx.x; i < 96 + 160*12 + 12; i += blockDim.x) {
            if (i < 96) {
                float s = 0.f;
                for (int h = 0; h < HH; h++) s += enc_w[h] * w_ih[i*HH + h];
                A[i] = s;
            } else if (i < 96 + 1920) {
                int j = i - 96; int c = j / 12, o = j % 12;
                float s = 0.f;
                for (int h = 0; h < HH; h++) s += filt_w[c*HH + h] * dec_w[h*12 + o];
                W2[j] = s;
            } else {
                int o = i - 2016;
                float s = dec_b[o];
                for (int h = 0; h < HH; h++) s += filt_b[h] * dec_w[h*12 + o];
                b2[o] = s;
            }
        }
        return;
    }
    int id = blockIdx.x * blockDim.x + threadIdx.x;  // N*96 exactly
    int n = id / 96, g = id % 96;
    float s = b_ih[g] + (g < 2*HH ? b_hh[g] : 0.f);
    const float* ne = node_emb + (size_t)n * HH;
    #pragma unroll
    for (int h = 0; h < HH; h++) s += (enc_b[h] + ne[h]) * w_ih[g*HH + h];
    CB[id] = s;
}

// ---- histogram of edge endpoints + weighted degrees
__global__ void k_hist(const int* __restrict__ ei, const float* __restrict__ ew,
                       int* cnt_f, int* cnt_b, float* deg_f, float* deg_b) {
    int e = blockIdx.x * blockDim.x + threadIdx.x;  // EE exactly
    int s = ei[e], t = ei[EE + e];
    float w = ew[e];
    atomicAdd(&cnt_f[t], 1); atomicAdd(&deg_f[t], w);
    atomicAdd(&cnt_b[s], 1); atomicAdd(&deg_b[s], w);
}

// ---- single-block exclusive scan (2 blocks: fwd / bwd) + inv-degree
__global__ void k_scan(const int* __restrict__ cnt_f, const float* __restrict__ deg_f,
                       int* off_f, int* cur_f, float* inv_f,
                       const int* __restrict__ cnt_b, const float* __restrict__ deg_b,
                       int* off_b, int* cur_b, float* inv_b) {
    const int* cnt; const float* deg; int* off; int* cur; float* inv;
    if (blockIdx.x == 0) { cnt = cnt_f; deg = deg_f; off = off_f; cur = cur_f; inv = inv_f; }
    else                 { cnt = cnt_b; deg = deg_b; off = off_b; cur = cur_b; inv = inv_b; }
    __shared__ int part[1024];
    int t = threadIdx.x;
    const int CH = (NN + 1023) / 1024;  // 10
    int beg = t * CH, end = min(beg + CH, NN);
    int s = 0;
    for (int i = beg; i < end; i++) s += cnt[i];
    part[t] = s;
    __syncthreads();
    for (int d = 1; d < 1024; d <<= 1) {
        int add = (t >= d) ? part[t - d] : 0;
        __syncthreads();
        part[t] += add;
        __syncthreads();
    }
    int run = part[t] - s;  // exclusive base
    for (int i = beg; i < end; i++) {
        off[i] = run; cur[i] = run; run += cnt[i];
        float dv = deg[i];
        inv[i] = dv > 0.f ? 1.0f / dv : 1.0f;
    }
    if (t == 1023) off[NN] = part[1023];
}

// ---- scatter edges into CSR buckets; weights pre-scaled by inv-degree
__global__ void k_fill(const int* __restrict__ ei, const float* __restrict__ ew,
                       const float* __restrict__ inv_f, const float* __restrict__ inv_b,
                       int* cur_f, int* csr_f_idx, float* csr_f_w,
                       int* cur_b, int* csr_b_idx, float* csr_b_w) {
    int e = blockIdx.x * blockDim.x + threadIdx.x;  // EE exactly
    int s = ei[e], t = ei[EE + e]; float w = ew[e];
    int pf = atomicAdd(&cur_f[t], 1); csr_f_idx[pf] = s; csr_f_w[pf] = w * inv_f[t];
    int pb = atomicAdd(&cur_b[s], 1); csr_b_idx[pb] = t; csr_b_w[pb] = w * inv_b[s];
}

// ---- fused GRU over T=12, thread = (2 rows, j): h in LDS, weights from LDS
// Block 256 = 8 groups x 32 j; group g owns rows r0+g and r0+g+8. Wave owns its
// 4 rows entirely -> intra-wave exchange via ds_write + lgkmcnt(0), no barrier.
// Outputs: fp32 [n][b][h] (for decoder) + fp16 [n][b][h] (for diffusion gather).
__global__ __launch_bounds__(256) void k_gru(const float* __restrict__ x,
                      const float* __restrict__ CB, const float* __restrict__ Ag,
                      const float* __restrict__ w_hh, const float* __restrict__ b_hh,
                      float* __restrict__ hout, __half* __restrict__ hout16) {
    __shared__ float swt[96*36];
    __shared__ float sh[16*36];
    int tid = threadIdx.x;
    for (int i = tid; i < 96*32; i += 256) {
        int g = i >> 5, h = i & 31;
        swt[g*36 + h] = w_hh[i];
    }
    __syncthreads();

    const int j = tid & 31, g = tid >> 5;     // g in 0..7
    int r0 = blockIdx.x * 16;                 // 5000 blocks -> 80000 rows
    int rA = r0 + g, rB = r0 + g + 8;
    int bA = rA / NN, nA = rA - bA * NN;
    int bB = rB / NN, nB = rB - bB * NN;

    const float* cA = CB + (size_t)nA * 96;
    const float* cBp = CB + (size_t)nB * 96;
    float cbRA = cA[j],  cbZA = cA[32+j],  cbNA = cA[64+j];
    float cbRB = cBp[j], cbZB = cBp[32+j], cbNB = cBp[64+j];
    float bn0 = b_hh[64+j];
    float aR = Ag[j], aZ = Ag[32+j], aN = Ag[64+j];

    float xA[12], xB[12];
    const float* xpA = x + (size_t)bA * TT * NN + nA;
    const float* xpB = x + (size_t)bB * TT * NN + nB;
    #pragma unroll
    for (int t = 0; t < TT; t++) { xA[t] = xpA[(size_t)t * NN]; xB[t] = xpB[(size_t)t * NN]; }

    float* shA = sh + g * 36;
    float* shB = sh + (g + 8) * 36;

    float ownA, ownB;
    {   // t = 0: h = 0
        float rrA = sigm(fmaf(xA[0], aR, cbRA));
        float zzA = sigm(fmaf(xA[0], aZ, cbZA));
        float nvA = tanh_fast(fmaf(xA[0], aN, cbNA) + rrA * bn0);
        ownA = (1.f - zzA) * nvA;
        float rrB = sigm(fmaf(xB[0], aR, cbRB));
        float zzB = sigm(fmaf(xB[0], aZ, cbZB));
        float nvB = tanh_fast(fmaf(xB[0], aN, cbNB) + rrB * bn0);
        ownB = (1.f - zzB) * nvB;
    }
    shA[j] = ownA;
    shB[j] = ownB;

    #pragma unroll 1
    for (int t = 1; t < TT; t++) {
        asm volatile("s_waitcnt lgkmcnt(0)" ::: "memory");
        float grA = 0.f, gzA = 0.f, gnA = bn0;
        float grB = 0.f, gzB = 0.f, gnB = bn0;
        #pragma unroll
        for (int q = 0; q < 8; q++) {
            float4 hA = *(const float4*)(shA + 4*q);
            float4 hB = *(const float4*)(shB + 4*q);
            float4 w0 = *(const float4*)(swt + j*36      + 4*q);
            float4 w1 = *(const float4*)(swt + (32+j)*36 + 4*q);
            float4 w2 = *(const float4*)(swt + (64+j)*36 + 4*q);
            grA = fmaf(hA.x, w0.x, grA); grA = fmaf(hA.y, w0.y, grA);
            grA = fmaf(hA.z, w0.z, grA); grA = fmaf(hA.w, w0.w, grA);
            gzA = fmaf(hA.x, w1.x, gzA); gzA = fmaf(hA.y, w1.y, gzA);
            gzA = fmaf(hA.z, w1.z, gzA); gzA = fmaf(hA.w, w1.w, gzA);
            gnA = fmaf(hA.x, w2.x, gnA); gnA = fmaf(hA.y, w2.y, gnA);
            gnA = fmaf(hA.z, w2.z, gnA); gnA = fmaf(hA.w, w2.w, gnA);
            grB = fmaf(hB.x, w0.x, grB); grB = fmaf(hB.y, w0.y, grB);
            grB = fmaf(hB.z, w0.z, grB); grB = fmaf(hB.w, w0.w, grB);
            gzB = fmaf(hB.x, w1.x, gzB); gzB = fmaf(hB.y, w1.y, gzB);
            gzB = fmaf(hB.z, w1.z, gzB); gzB = fmaf(hB.w, w1.w, gzB);
            gnB = fmaf(hB.x, w2.x, gnB); gnB = fmaf(hB.y, w2.y, gnB);
            gnB = fmaf(hB.z, w2.z, gnB); gnB = fmaf(hB.w, w2.w, gnB);
        }
        float rrA = sigm(fmaf(xA[t], aR, cbRA) + grA);
        float zzA = sigm(fmaf(xA[t], aZ, cbZA) + gzA);
        float nvA = tanh_fast(fmaf(xA[t], aN, cbNA) + rrA * gnA);
        ownA = (1.f - zzA) * nvA + zzA * ownA;
        float rrB = sigm(fmaf(xB[t], aR, cbRB) + grB);
        float zzB = sigm(fmaf(xB[t], aZ, cbZB) + gzB);
        float nvB = tanh_fast(fmaf(xB[t], aN, cbNB) + rrB * gnB);
        ownB = (1.f - zzB) * nvB + zzB * ownB;
        if (t < TT-1) { shA[j] = ownA; shB[j] = ownB; }
    }
    size_t iA = ((size_t)nA * BB + bA) * HH + j;
    size_t iB = ((size_t)nB * BB + bB) * HH + j;
    hout[iA] = ownA;               hout[iB] = ownB;
    hout16[iA] = __float2half(ownA); hout16[iB] = __float2half(ownB);
}

// ---- dual-direction diffusion hop, fp16 gather / fp32+fp16 outputs
// wave per node: lane l handles dwords l and l+64 of the 128-dword (256 fp16)
// row [b][h]. Per edge: 2 coalesced 4B loads per lane (256B/wave each), fp32
// accum. Unroll 4 edges -> 8 row-loads + idx/w in flight. Weights pre-scaled.
__global__ __launch_bounds__(256) void k_prop(
        const __half* __restrict__ xF, const __half* __restrict__ xB,
        float* __restrict__ yF, float* __restrict__ yB,
        __half* __restrict__ yF16, __half* __restrict__ yB16,
        const int* __restrict__ offF, const int* __restrict__ idxF, const float* __restrict__ wF,
        const int* __restrict__ offB, const int* __restrict__ idxB, const float* __restrict__ wB) {
    int wid = threadIdx.x >> 6;         // 0..3
    int l   = threadIdx.x & 63;
    int n = blockIdx.x * 4 + wid;       // 2500 blocks exactly
    const unsigned* xu;
    float a00, a01, a10, a11;

    #pragma unroll 2
    for (int dir = 0; dir < 2; dir++) {
        const int* off; const int* idx; const float* w;
        if (dir == 0) { xu = (const unsigned*)xF; off = offF; idx = idxF; w = wF; }
        else          { xu = (const unsigned*)xB; off = offB; idx = idxB; w = wB; }
        int e0 = off[n], e1 = off[n+1];
        a00 = a01 = a10 = a11 = 0.f;
        int e = e0;
        for (; e + 4 <= e1; e += 4) {
            int   s0 = idx[e],   s1 = idx[e+1], s2 = idx[e+2], s3 = idx[e+3];
            float w0 = w[e],     w1 = w[e+1],   w2 = w[e+2],   w3 = w[e+3];
            unsigned u00 = xu[((size_t)s0 << 7) + l], u01 = xu[((size_t)s0 << 7) + 64 + l];
            unsigned u10 = xu[((size_t)s1 << 7) + l], u11 = xu[((size_t)s1 << 7) + 64 + l];
            unsigned u20 = xu[((size_t)s2 << 7) + l], u21 = xu[((size_t)s2 << 7) + 64 + l];
            unsigned u30 = xu[((size_t)s3 << 7) + l], u31 = xu[((size_t)s3 << 7) + 64 + l];
            float2 f;
            f = uph2(u00); a00 = fmaf(w0, f.x, a00); a01 = fmaf(w0, f.y, a01);
            f = uph2(u01); a10 = fmaf(w0, f.x, a10); a11 = fmaf(w0, f.y, a11);
            f = uph2(u10); a00 = fmaf(w1, f.x, a00); a01 = fmaf(w1, f.y, a01);
            f = uph2(u11); a10 = fmaf(w1, f.x, a10); a11 = fmaf(w1, f.y, a11);
            f = uph2(u20); a00 = fmaf(w2, f.x, a00); a01 = fmaf(w2, f.y, a01);
            f = uph2(u21); a10 = fmaf(w2, f.x, a10); a11 = fmaf(w2, f.y, a11);
            f = uph2(u30); a00 = fmaf(w3, f.x, a00); a01 = fmaf(w3, f.y, a01);
            f = uph2(u31); a10 = fmaf(w3, f.x, a10); a11 = fmaf(w3, f.y, a11);
        }
        for (; e < e1; ++e) {
            int s0 = idx[e]; float w0 = w[e];
            unsigned u0 = xu[((size_t)s0 << 7) + l], u1 = xu[((size_t)s0 << 7) + 64 + l];
            float2 f;
            f = uph2(u0); a00 = fmaf(w0, f.x, a00); a01 = fmaf(w0, f.y, a01);
            f = uph2(u1); a10 = fmaf(w0, f.x, a10); a11 = fmaf(w0, f.y, a11);
        }
        float*    yf  = (dir == 0) ? yF : yB;
        unsigned* yh  = (unsigned*)((dir == 0) ? yF16 : yB16);
        float2 o0; o0.x = a00; o0.y = a01;
        float2 o1; o1.x = a10; o1.y = a11;
        *(float2*)(yf + ((size_t)n << 8) + 2*l)       = o0;
        *(float2*)(yf + ((size_t)n << 8) + 128 + 2*l) = o1;
        yh[((size_t)n << 7) + l]      = pkh2(a00, a01);
        yh[((size_t)n << 7) + 64 + l] = pkh2(a10, a11);
    }
}

// ---- fused decoder: out[b,t,n] = b2[t] + sum_{pi,c} piece_pi[n,b,c] * W2[pi*32+c, t]
__global__ __launch_bounds__(256) void k_dec(const float* __restrict__ p0,
                     const float* __restrict__ p1, const float* __restrict__ p2,
                     const float* __restrict__ p3, const float* __restrict__ p4,
                     const float* __restrict__ W2, const float* __restrict__ b2,
                     float* __restrict__ out) {
    __shared__ float sW[1920];
    __shared__ float sb[12];
    int tid = threadIdx.x;
    for (int i = tid; i < 1920; i += 256) sW[i] = W2[i];
    if (tid < 12) sb[tid] = b2[tid];
    __syncthreads();
    int r = blockIdx.x * 256 + tid;
    if (r >= BB*NN) return;
    int b = r / NN, n = r - b*NN;
    size_t base = ((size_t)n * BB + b) * HH;
    float a[12];
    #pragma unroll
    for (int o = 0; o < 12; o++) a[o] = sb[o];
    const float* ps[5] = {p0, p1, p2, p3, p4};
    #pragma unroll
    for (int pi = 0; pi < 5; pi++) {
        const float4* pp = (const float4*)(ps[pi] + base);
        #pragma unroll
        for (int q = 0; q < 8; q++) {
            float4 v = pp[q];
            float pv[4] = {v.x, v.y, v.z, v.w};
            #pragma unroll
            for (int k = 0; k < 4; k++) {
                const float* wrow = sW + (pi*32 + 4*q + k) * 12;
                #pragma unroll
                for (int o = 0; o < 12; o++) a[o] = fmaf(pv[k], wrow[o], a[o]);
            }
        }
    }
    #pragma unroll
    for (int t = 0; t < HOR; t++)
        out[((size_t)(b*HOR + t))*NN + n] = a[t];
}

extern "C" void kernel_launch(void* const* d_in, const int* in_sizes, int n_in,
                              void* d_out, int out_size, void* d_ws, size_t ws_size,
                              hipStream_t stream) {
    const float* x      = (const float*)d_in[0];
    const int*   ei     = (const int*)d_in[1];
    const float* ew     = (const float*)d_in[2];
    const float* enc_w  = (const float*)d_in[3];
    const float* enc_b  = (const float*)d_in[4];
    const float* nemb   = (const float*)d_in[5];
    const float* w_ih   = (const float*)d_in[6];
    const float* w_hh   = (const float*)d_in[7];
    const float* b_ih   = (const float*)d_in[8];
    const float* b_hh   = (const float*)d_in[9];
    const float* filt_w = (const float*)d_in[10];
    const float* filt_b = (const float*)d_in[11];
    const float* dec_w  = (const float*)d_in[12];
    const float* dec_b  = (const float*)d_in[13];
    float* out = (float*)d_out;

    char* p = (char*)d_ws;
    auto alloc = [&](size_t bytes) -> char* {
        char* q = p; p += (bytes + 255) & ~(size_t)255; return q;
    };
    // zero-region (single memset): cnt_f, cnt_b, deg_f, deg_b
    char* zero_base = p;
    int*   cnt_f = (int*)  alloc((size_t)NN*4);
    int*   cnt_b = (int*)  alloc((size_t)NN*4);
    float* deg_f = (float*)alloc((size_t)NN*4);
    float* deg_b = (float*)alloc((size_t)NN*4);
    size_t zero_bytes = (size_t)(p - zero_base);

    const size_t SROW = (size_t)BB*NN*HH;
    float*  h_time = (float*)alloc(SROW*4);
    float*  yA     = (float*)alloc(SROW*4);
    float*  yB     = (float*)alloc(SROW*4);
    float*  yC     = (float*)alloc(SROW*4);
    float*  yD     = (float*)alloc(SROW*4);
    __half* h16    = (__half*)alloc(SROW*2);
    __half* a16    = (__half*)alloc(SROW*2);
    __half* b16    = (__half*)alloc(SROW*2);
    __half* c16    = (__half*)alloc(SROW*2);
    __half* d16    = (__half*)alloc(SROW*2);
    float* CB     = (float*)alloc((size_t)NN*96*4);
    float* A      = (float*)alloc(96*4);
    float* W2     = (float*)alloc(1920*4);
    float* b2     = (float*)alloc(12*4);
    float* inv_f  = (float*)alloc((size_t)NN*4);
    float* inv_b  = (float*)alloc((size_t)NN*4);
    int*   off_f  = (int*)  alloc((size_t)(NN+1)*4);
    int*   off_b  = (int*)  alloc((size_t)(NN+1)*4);
    int*   cur_f  = (int*)  alloc((size_t)NN*4);
    int*   cur_b  = (int*)  alloc((size_t)NN*4);
    int*   cfi    = (int*)  alloc((size_t)EE*4);
    float* cfw    = (float*)alloc((size_t)EE*4);
    int*   cbi    = (int*)  alloc((size_t)EE*4);
    float* cbw    = (float*)alloc((size_t)EE*4);

    hipMemsetAsync(zero_base, 0, zero_bytes, stream);

    k_cb<<<NN*96/256 + 1, 256, 0, stream>>>(nemb, enc_b, w_ih, b_ih, b_hh,
                                            enc_w, filt_w, filt_b, dec_w, dec_b,
                                            CB, A, W2, b2);
    k_hist<<<EE/256, 256, 0, stream>>>(ei, ew, cnt_f, cnt_b, deg_f, deg_b);
    k_scan<<<2, 1024, 0, stream>>>(cnt_f, deg_f, off_f, cur_f, inv_f,
                                   cnt_b, deg_b, off_b, cur_b, inv_b);
    k_fill<<<EE/256, 256, 0, stream>>>(ei, ew, inv_f, inv_b,
                                       cur_f, cfi, cfw, cur_b, cbi, cbw);

    k_gru<<<5000, 256, 0, stream>>>(x, CB, A, w_hh, b_hh, h_time, h16);

    k_prop<<<2500, 256, 0, stream>>>(h16, h16, yA, yC, a16, c16,
                                     off_f, cfi, cfw, off_b, cbi, cbw);
    k_prop<<<2500, 256, 0, stream>>>(a16, c16, yB, yD, b16, d16,
                                     off_f, cfi, cfw, off_b, cbi, cbw);

    k_dec<<<(BB*NN + 255)/256, 256, 0, stream>>>(h_time, yA, yB, yC, yD, W2, b2, out);
}

// Round 7
// 309.979 us; speedup vs baseline: 7.8417x; 1.1116x over previous
//
#include <hip/hip_runtime.h>
#include <hip/hip_fp16.h>

#define BB 8
#define TT 12
#define NN 10000
#define HH 32
#define EE 320000
#define HOR 12

static __device__ __forceinline__ float sigm(float x) {
    return __builtin_amdgcn_rcpf(1.0f + __expf(-x));
}
static __device__ __forceinline__ float tanh_fast(float x) {
    return 1.0f - 2.0f * __builtin_amdgcn_rcpf(1.0f + __expf(2.0f * x));
}
static __device__ __forceinline__ float2 uph2(unsigned u) {
    __half2 h = *(__half2*)&u;
    return __half22float2(h);
}
static __device__ __forceinline__ unsigned pkh2(float a, float b) {
    __half2 h = __floats2half2_rn(a, b);
    return *(unsigned*)&h;
}
typedef _Float16 h2_t __attribute__((ext_vector_type(2)));
static __device__ __forceinline__ float dot2(unsigned a, unsigned b, float c) {
    return __builtin_amdgcn_fdot2(__builtin_bit_cast(h2_t, a),
                                  __builtin_bit_cast(h2_t, b), c, false);
}

// 16 dot2 (= 32 MAC) with two chains
#define D16(P, Q, W0,W1,W2,W3, H0,H1,H2,H3) \
    P = dot2(W0.x,H0.x,P); Q = dot2(W0.y,H0.y,Q); P = dot2(W0.z,H0.z,P); Q = dot2(W0.w,H0.w,Q); \
    P = dot2(W1.x,H1.x,P); Q = dot2(W1.y,H1.y,Q); P = dot2(W1.z,H1.z,P); Q = dot2(W1.w,H1.w,Q); \
    P = dot2(W2.x,H2.x,P); Q = dot2(W2.y,H2.y,Q); P = dot2(W2.z,H2.z,P); Q = dot2(W2.w,H2.w,Q); \
    P = dot2(W3.x,H3.x,P); Q = dot2(W3.y,H3.y,Q); P = dot2(W3.z,H3.z,P); Q = dot2(W3.w,H3.w,Q);

// ---- fused: CB precompute (blocks 0..3749), tiny prep (block 3750), edge histogram (3751..5000)
__global__ void k_cbhist(const float* __restrict__ node_emb, const float* __restrict__ enc_b,
                     const float* __restrict__ w_ih, const float* __restrict__ b_ih,
                     const float* __restrict__ b_hh,
                     const float* __restrict__ enc_w, const float* __restrict__ filt_w,
                     const float* __restrict__ filt_b, const float* __restrict__ dec_w,
                     const float* __restrict__ dec_b,
                     float* __restrict__ CB, float* __restrict__ A,
                     float* __restrict__ W2, float* __restrict__ b2,
                     const int* __restrict__ ei, const float* __restrict__ ew,
                     int* cnt_f, int* cnt_b, float* deg_f, float* deg_b) {
    int bid = blockIdx.x;
    if (bid < 3750) {            // CB
        int id = bid * 256 + threadIdx.x;
        int n = id / 96, g = id % 96;
        float s = b_ih[g] + (g < 2*HH ? b_hh[g] : 0.f);
        const float* ne = node_emb + (size_t)n * HH;
        #pragma unroll
        for (int h = 0; h < HH; h++) s += (enc_b[h] + ne[h]) * w_ih[g*HH + h];
        CB[id] = s;
    } else if (bid == 3750) {    // prep
        for (int i = threadIdx.x; i < 96 + 160*12 + 12; i += blockDim.x) {
            if (i < 96) {
                float s = 0.f;
                for (int h = 0; h < HH; h++) s += enc_w[h] * w_ih[i*HH + h];
                A[i] = s;
            } else if (i < 96 + 1920) {
                int j = i - 96; int c = j / 12, o = j % 12;
                float s = 0.f;
                for (int h = 0; h < HH; h++) s += filt_w[c*HH + h] * dec_w[h*12 + o];
                W2[j] = s;
            } else {
                int o = i - 2016;
                float s = dec_b[o];
                for (int h = 0; h < HH; h++) s += filt_b[h] * dec_w[h*12 + o];
                b2[o] = s;
            }
        }
    } else {                     // hist
        int e = (bid - 3751) * 256 + threadIdx.x;
        int s = ei[e], t = ei[EE + e];
        float w = ew[e];
        atomicAdd(&cnt_f[t], 1); atomicAdd(&deg_f[t], w);
        atomicAdd(&cnt_b[s], 1); atomicAdd(&deg_b[s], w);
    }
}

// ---- single-block exclusive scan (2 blocks: fwd / bwd) + inv-degree
__global__ void k_scan(const int* __restrict__ cnt_f, const float* __restrict__ deg_f,
                       int* off_f, int* cur_f, float* inv_f,
                       const int* __restrict__ cnt_b, const float* __restrict__ deg_b,
                       int* off_b, int* cur_b, float* inv_b) {
    const int* cnt; const float* deg; int* off; int* cur; float* inv;
    if (blockIdx.x == 0) { cnt = cnt_f; deg = deg_f; off = off_f; cur = cur_f; inv = inv_f; }
    else                 { cnt = cnt_b; deg = deg_b; off = off_b; cur = cur_b; inv = inv_b; }
    __shared__ int part[1024];
    int t = threadIdx.x;
    const int CH = (NN + 1023) / 1024;  // 10
    int beg = t * CH, end = min(beg + CH, NN);
    int s = 0;
    for (int i = beg; i < end; i++) s += cnt[i];
    part[t] = s;
    __syncthreads();
    for (int d = 1; d < 1024; d <<= 1) {
        int add = (t >= d) ? part[t - d] : 0;
        __syncthreads();
        part[t] += add;
        __syncthreads();
    }
    int run = part[t] - s;  // exclusive base
    for (int i = beg; i < end; i++) {
        off[i] = run; cur[i] = run; run += cnt[i];
        float dv = deg[i];
        inv[i] = dv > 0.f ? 1.0f / dv : 1.0f;
    }
    if (t == 1023) off[NN] = part[1023];
}

// ---- scatter edges into CSR buckets; weights pre-scaled by inv-degree
__global__ void k_fill(const int* __restrict__ ei, const float* __restrict__ ew,
                       const float* __restrict__ inv_f, const float* __restrict__ inv_b,
                       int* cur_f, int* csr_f_idx, float* csr_f_w,
                       int* cur_b, int* csr_b_idx, float* csr_b_w) {
    int e = blockIdx.x * blockDim.x + threadIdx.x;  // EE exactly
    int s = ei[e], t = ei[EE + e]; float w = ew[e];
    int pf = atomicAdd(&cur_f[t], 1); csr_f_idx[pf] = s; csr_f_w[pf] = w * inv_f[t];
    int pb = atomicAdd(&cur_b[s], 1); csr_b_idx[pb] = t; csr_b_w[pb] = w * inv_b[s];
}

// ---- fused GRU over T=12, thread = (2 rows, j); fp16 w+h in LDS, v_dot2_f32_f16
// Block 256 = 8 groups x 32 j; group g owns rows r0+g and r0+g+8. Each wave owns
// its 4 rows entirely -> intra-wave exchange via ds_write_b16 + lgkmcnt(0), no
// barrier. Row stride 20 dwords (80B: b128-aligned; w-reads 4-way aliased, hidden
// under VALU). 96 dot2 + ~45 misc per step vs 192 fma + ~75 before.
__global__ __launch_bounds__(256) void k_gru(const float* __restrict__ x,
                      const float* __restrict__ CB, const float* __restrict__ Ag,
                      const float* __restrict__ w_hh, const float* __restrict__ b_hh,
                      float* __restrict__ hout, __half* __restrict__ hout16) {
    __shared__ unsigned swt[96*20];
    __shared__ unsigned sh[16*20];
    int tid = threadIdx.x;
    for (int i = tid; i < 96*16; i += 256) {   // 1536 half2 dwords
        int g = i >> 4, d = i & 15;
        float2 wv = *(const float2*)(w_hh + g*32 + 2*d);
        swt[g*20 + d] = pkh2(wv.x, wv.y);
    }
    __syncthreads();

    const int j = tid & 31, g = tid >> 5;     // g in 0..7
    int r0 = blockIdx.x * 16;                 // 5000 blocks -> 80000 rows
    int rA = r0 + g, rB = r0 + g + 8;
    int bA = rA / NN, nA = rA - bA * NN;
    int bB = rB / NN, nB = rB - bB * NN;

    const float* cA = CB + (size_t)nA * 96;
    const float* cBp = CB + (size_t)nB * 96;
    float cbRA = cA[j],  cbZA = cA[32+j],  cbNA = cA[64+j];
    float cbRB = cBp[j], cbZB = cBp[32+j], cbNB = cBp[64+j];
    float bn0 = b_hh[64+j];
    float aR = Ag[j], aZ = Ag[32+j], aN = Ag[64+j];

    float xA[12], xB[12];
    const float* xpA = x + (size_t)bA * TT * NN + nA;
    const float* xpB = x + (size_t)bB * TT * NN + nB;
    #pragma unroll
    for (int t = 0; t < TT; t++) { xA[t] = xpA[(size_t)t * NN]; xB[t] = xpB[(size_t)t * NN]; }

    __half* shh = (__half*)sh;
    float ownA, ownB;
    {   // t = 0: h = 0
        float rrA = sigm(fmaf(xA[0], aR, cbRA));
        float zzA = sigm(fmaf(xA[0], aZ, cbZA));
        float nvA = tanh_fast(fmaf(xA[0], aN, cbNA) + rrA * bn0);
        ownA = (1.f - zzA) * nvA;
        float rrB = sigm(fmaf(xB[0], aR, cbRB));
        float zzB = sigm(fmaf(xB[0], aZ, cbZB));
        float nvB = tanh_fast(fmaf(xB[0], aN, cbNB) + rrB * bn0);
        ownB = (1.f - zzB) * nvB;
    }
    shh[g*40 + j]     = __float2half_rn(ownA);
    shh[(g+8)*40 + j] = __float2half_rn(ownB);

    const uint4* wR = (const uint4*)(swt + j*20);
    const uint4* wZ = (const uint4*)(swt + (32+j)*20);
    const uint4* wN = (const uint4*)(swt + (64+j)*20);
    const uint4* hA = (const uint4*)(sh + g*20);
    const uint4* hB = (const uint4*)(sh + (g+8)*20);

    #pragma unroll 1
    for (int t = 1; t < TT; t++) {
        asm volatile("s_waitcnt lgkmcnt(0)" ::: "memory");
        uint4 ha0 = hA[0], ha1 = hA[1], ha2 = hA[2], ha3 = hA[3];
        uint4 hb0 = hB[0], hb1 = hB[1], hb2 = hB[2], hb3 = hB[3];
        uint4 wr0 = wR[0], wr1 = wR[1], wr2 = wR[2], wr3 = wR[3];
        uint4 wz0 = wZ[0], wz1 = wZ[1], wz2 = wZ[2], wz3 = wZ[3];
        uint4 wn0 = wN[0], wn1 = wN[1], wn2 = wN[2], wn3 = wN[3];

        float pRA = 0.f, qRA = 0.f, pZA = 0.f, qZA = 0.f, pNA = bn0, qNA = 0.f;
        D16(pRA, qRA, wr0,wr1,wr2,wr3, ha0,ha1,ha2,ha3);
        D16(pZA, qZA, wz0,wz1,wz2,wz3, ha0,ha1,ha2,ha3);
        D16(pNA, qNA, wn0,wn1,wn2,wn3, ha0,ha1,ha2,ha3);
        float pRB = 0.f, qRB = 0.f, pZB = 0.f, qZB = 0.f, pNB = bn0, qNB = 0.f;
        D16(pRB, qRB, wr0,wr1,wr2,wr3, hb0,hb1,hb2,hb3);
        D16(pZB, qZB, wz0,wz1,wz2,wz3, hb0,hb1,hb2,hb3);
        D16(pNB, qNB, wn0,wn1,wn2,wn3, hb0,hb1,hb2,hb3);

        float rrA = sigm(fmaf(xA[t], aR, cbRA) + pRA + qRA);
        float zzA = sigm(fmaf(xA[t], aZ, cbZA) + pZA + qZA);
        float nvA = tanh_fast(fmaf(xA[t], aN, cbNA) + rrA * (pNA + qNA));
        ownA = (1.f - zzA) * nvA + zzA * ownA;
        float rrB = sigm(fmaf(xB[t], aR, cbRB) + pRB + qRB);
        float zzB = sigm(fmaf(xB[t], aZ, cbZB) + pZB + qZB);
        float nvB = tanh_fast(fmaf(xB[t], aN, cbNB) + rrB * (pNB + qNB));
        ownB = (1.f - zzB) * nvB + zzB * ownB;
        if (t < TT-1) {
            shh[g*40 + j]     = __float2half_rn(ownA);
            shh[(g+8)*40 + j] = __float2half_rn(ownB);
        }
    }
    size_t iA = ((size_t)nA * BB + bA) * HH + j;
    size_t iB = ((size_t)nB * BB + bB) * HH + j;
    hout[iA] = ownA;                 hout[iB] = ownB;
    hout16[iA] = __float2half(ownA); hout16[iB] = __float2half(ownB);
}

// ---- diffusion hop: wave = (node, dir); lane handles halves 4l..4l+3
// Per edge: ONE dwordx2 per lane (512B/wave, coalesced), fp32 accum, 4-edge
// unroll. 20000 waves for latency hiding. CSR weights pre-scaled by inv-degree.
__global__ __launch_bounds__(256) void k_prop(
        const __half* __restrict__ xF, const __half* __restrict__ xB,
        float* __restrict__ yF, float* __restrict__ yB,
        __half* __restrict__ yF16, __half* __restrict__ yB16,
        const int* __restrict__ offF, const int* __restrict__ idxF, const float* __restrict__ wF,
        const int* __restrict__ offB, const int* __restrict__ idxB, const float* __restrict__ wB) {
    int wid = threadIdx.x >> 6;         // 0..3
    int l   = threadIdx.x & 63;
    int nd = blockIdx.x * 4 + wid;      // 5000 blocks -> 20000 = NN*2
    int n = nd >> 1, dir = nd & 1;
    const unsigned* xu = (const unsigned*)(dir ? xB : xF);
    const int* off = dir ? offB : offF;
    const int* idx = dir ? idxB : idxF;
    const float* w = dir ? wB : wF;

    int e0 = off[n], e1 = off[n+1];
    float a0 = 0.f, a1 = 0.f, a2 = 0.f, a3 = 0.f;
    int e = e0;
    for (; e + 4 <= e1; e += 4) {
        int   s0 = idx[e],   s1 = idx[e+1], s2 = idx[e+2], s3 = idx[e+3];
        float w0 = w[e],     w1 = w[e+1],   w2 = w[e+2],   w3 = w[e+3];
        uint2 u0 = *(const uint2*)(xu + ((size_t)s0 << 7) + 2*l);
        uint2 u1 = *(const uint2*)(xu + ((size_t)s1 << 7) + 2*l);
        uint2 u2 = *(const uint2*)(xu + ((size_t)s2 << 7) + 2*l);
        uint2 u3 = *(const uint2*)(xu + ((size_t)s3 << 7) + 2*l);
        float2 f;
        f = uph2(u0.x); a0 = fmaf(w0, f.x, a0); a1 = fmaf(w0, f.y, a1);
        f = uph2(u0.y); a2 = fmaf(w0, f.x, a2); a3 = fmaf(w0, f.y, a3);
        f = uph2(u1.x); a0 = fmaf(w1, f.x, a0); a1 = fmaf(w1, f.y, a1);
        f = uph2(u1.y); a2 = fmaf(w1, f.x, a2); a3 = fmaf(w1, f.y, a3);
        f = uph2(u2.x); a0 = fmaf(w2, f.x, a0); a1 = fmaf(w2, f.y, a1);
        f = uph2(u2.y); a2 = fmaf(w2, f.x, a2); a3 = fmaf(w2, f.y, a3);
        f = uph2(u3.x); a0 = fmaf(w3, f.x, a0); a1 = fmaf(w3, f.y, a1);
        f = uph2(u3.y); a2 = fmaf(w3, f.x, a2); a3 = fmaf(w3, f.y, a3);
    }
    for (; e < e1; ++e) {
        int s0 = idx[e]; float w0 = w[e];
        uint2 u0 = *(const uint2*)(xu + ((size_t)s0 << 7) + 2*l);
        float2 f;
        f = uph2(u0.x); a0 = fmaf(w0, f.x, a0); a1 = fmaf(w0, f.y, a1);
        f = uph2(u0.y); a2 = fmaf(w0, f.x, a2); a3 = fmaf(w0, f.y, a3);
    }
    float*    yf = dir ? yB : yF;
    unsigned* yh = (unsigned*)(dir ? yB16 : yF16);
    float4 o; o.x = a0; o.y = a1; o.z = a2; o.w = a3;
    *(float4*)(yf + ((size_t)n << 8) + 4*l) = o;
    uint2 oh; oh.x = pkh2(a0, a1); oh.y = pkh2(a2, a3);
    *(uint2*)(yh + ((size_t)n << 7) + 2*l) = oh;
}

// ---- fused decoder: out[b,t,n] = b2[t] + sum_{pi,c} piece_pi[n,b,c] * W2[pi*32+c, t]
__global__ __launch_bounds__(256) void k_dec(const float* __restrict__ p0,
                     const float* __restrict__ p1, const float* __restrict__ p2,
                     const float* __restrict__ p3, const float* __restrict__ p4,
                     const float* __restrict__ W2, const float* __restrict__ b2,
                     float* __restrict__ out) {
    __shared__ float sW[1920];
    __shared__ float sb[12];
    int tid = threadIdx.x;
    for (int i = tid; i < 1920; i += 256) sW[i] = W2[i];
    if (tid < 12) sb[tid] = b2[tid];
    __syncthreads();
    int r = blockIdx.x * 256 + tid;
    if (r >= BB*NN) return;
    int b = r / NN, n = r - b*NN;
    size_t base = ((size_t)n * BB + b) * HH;
    float a[12];
    #pragma unroll
    for (int o = 0; o < 12; o++) a[o] = sb[o];
    const float* ps[5] = {p0, p1, p2, p3, p4};
    #pragma unroll
    for (int pi = 0; pi < 5; pi++) {
        const float4* pp = (const float4*)(ps[pi] + base);
        #pragma unroll
        for (int q = 0; q < 8; q++) {
            float4 v = pp[q];
            float pv[4] = {v.x, v.y, v.z, v.w};
            #pragma unroll
            for (int k = 0; k < 4; k++) {
                const float* wrow = sW + (pi*32 + 4*q + k) * 12;
                #pragma unroll
                for (int o = 0; o < 12; o++) a[o] = fmaf(pv[k], wrow[o], a[o]);
            }
        }
    }
    #pragma unroll
    for (int t = 0; t < HOR; t++)
        out[((size_t)(b*HOR + t))*NN + n] = a[t];
}

extern "C" void kernel_launch(void* const* d_in, const int* in_sizes, int n_in,
                              void* d_out, int out_size, void* d_ws, size_t ws_size,
                              hipStream_t stream) {
    const float* x      = (const float*)d_in[0];
    const int*   ei     = (const int*)d_in[1];
    const float* ew     = (const float*)d_in[2];
    const float* enc_w  = (const float*)d_in[3];
    const float* enc_b  = (const float*)d_in[4];
    const float* nemb   = (const float*)d_in[5];
    const float* w_ih   = (const float*)d_in[6];
    const float* w_hh   = (const float*)d_in[7];
    const float* b_ih   = (const float*)d_in[8];
    const float* b_hh   = (const float*)d_in[9];
    const float* filt_w = (const float*)d_in[10];
    const float* filt_b = (const float*)d_in[11];
    const float* dec_w  = (const float*)d_in[12];
    const float* dec_b  = (const float*)d_in[13];
    float* out = (float*)d_out;

    char* p = (char*)d_ws;
    auto alloc = [&](size_t bytes) -> char* {
        char* q = p; p += (bytes + 255) & ~(size_t)255; return q;
    };
    // zero-region (single memset): cnt_f, cnt_b, deg_f, deg_b
    char* zero_base = p;
    int*   cnt_f = (int*)  alloc((size_t)NN*4);
    int*   cnt_b = (int*)  alloc((size_t)NN*4);
    float* deg_f = (float*)alloc((size_t)NN*4);
    float* deg_b = (float*)alloc((size_t)NN*4);
    size_t zero_bytes = (size_t)(p - zero_base);

    const size_t SROW = (size_t)BB*NN*HH;
    float*  h_time = (float*)alloc(SROW*4);
    float*  yA     = (float*)alloc(SROW*4);
    float*  yB     = (float*)alloc(SROW*4);
    float*  yC     = (float*)alloc(SROW*4);
    float*  yD     = (float*)alloc(SROW*4);
    __half* h16    = (__half*)alloc(SROW*2);
    __half* a16    = (__half*)alloc(SROW*2);
    __half* b16    = (__half*)alloc(SROW*2);
    __half* c16    = (__half*)alloc(SROW*2);
    __half* d16    = (__half*)alloc(SROW*2);
    float* CB     = (float*)alloc((size_t)NN*96*4);
    float* A      = (float*)alloc(96*4);
    float* W2     = (float*)alloc(1920*4);
    float* b2     = (float*)alloc(12*4);
    float* inv_f  = (float*)alloc((size_t)NN*4);
    float* inv_b  = (float*)alloc((size_t)NN*4);
    int*   off_f  = (int*)  alloc((size_t)(NN+1)*4);
    int*   off_b  = (int*)  alloc((size_t)(NN+1)*4);
    int*   cur_f  = (int*)  alloc((size_t)NN*4);
    int*   cur_b  = (int*)  alloc((size_t)NN*4);
    int*   cfi    = (int*)  alloc((size_t)EE*4);
    float* cfw    = (float*)alloc((size_t)EE*4);
    int*   cbi    = (int*)  alloc((size_t)EE*4);
    float* cbw    = (float*)alloc((size_t)EE*4);

    hipMemsetAsync(zero_base, 0, zero_bytes, stream);

    k_cbhist<<<5001, 256, 0, stream>>>(nemb, enc_b, w_ih, b_ih, b_hh,
                                       enc_w, filt_w, filt_b, dec_w, dec_b,
                                       CB, A, W2, b2,
                                       ei, ew, cnt_f, cnt_b, deg_f, deg_b);
    k_scan<<<2, 1024, 0, stream>>>(cnt_f, deg_f, off_f, cur_f, inv_f,
                                   cnt_b, deg_b, off_b, cur_b, inv_b);
    k_fill<<<EE/256, 256, 0, stream>>>(ei, ew, inv_f, inv_b,
                                       cur_f, cfi, cfw, cur_b, cbi, cbw);

    k_gru<<<5000, 256, 0, stream>>>(x, CB, A, w_hh, b_hh, h_time, h16);

    k_prop<<<5000, 256, 0, stream>>>(h16, h16, yA, yC, a16, c16,
                                     off_f, cfi, cfw, off_b, cbi, cbw);
    k_prop<<<5000, 256, 0, stream>>>(a16, c16, yB, yD, b16, d16,
                                     off_f, cfi, cfw, off_b, cbi, cbw);

    k_dec<<<(BB*NN + 255)/256, 256, 0, stream>>>(h_time, yA, yB, yC, yD, W2, b2, out);
}

// Round 8
// 300.186 us; speedup vs baseline: 8.0975x; 1.0326x over previous
//
#include <hip/hip_runtime.h>
#include <hip/hip_fp16.h>

#define BB 8
#define TT 12
#define NN 10000
#define HH 32
#define EE 320000
#define HOR 12

static __device__ __forceinline__ float sigm(float x) {
    return __builtin_amdgcn_rcpf(1.0f + __expf(-x));
}
static __device__ __forceinline__ float tanh_fast(float x) {
    return 1.0f - 2.0f * __builtin_amdgcn_rcpf(1.0f + __expf(2.0f * x));
}
static __device__ __forceinline__ float2 uph2(unsigned u) {
    __half2 h = *(__half2*)&u;
    return __half22float2(h);
}
static __device__ __forceinline__ unsigned pkh2(float a, float b) {
    __half2 h = __floats2half2_rn(a, b);
    return *(unsigned*)&h;
}
typedef _Float16 h2_t __attribute__((ext_vector_type(2)));
static __device__ __forceinline__ float dot2(unsigned a, unsigned b, float c) {
    return __builtin_amdgcn_fdot2(__builtin_bit_cast(h2_t, a),
                                  __builtin_bit_cast(h2_t, b), c, false);
}

// 16 dot2 (= 32 MAC) with two chains
#define D16(P, Q, W0,W1,W2,W3, H0,H1,H2,H3) \
    P = dot2(W0.x,H0.x,P); Q = dot2(W0.y,H0.y,Q); P = dot2(W0.z,H0.z,P); Q = dot2(W0.w,H0.w,Q); \
    P = dot2(W1.x,H1.x,P); Q = dot2(W1.y,H1.y,Q); P = dot2(W1.z,H1.z,P); Q = dot2(W1.w,H1.w,Q); \
    P = dot2(W2.x,H2.x,P); Q = dot2(W2.y,H2.y,Q); P = dot2(W2.z,H2.z,P); Q = dot2(W2.w,H2.w,Q); \
    P = dot2(W3.x,H3.x,P); Q = dot2(W3.y,H3.y,Q); P = dot2(W3.z,H3.z,P); Q = dot2(W3.w,H3.w,Q);

// ---- fused: CB precompute (blocks 0..3749), tiny prep (block 3750), edge histogram (3751..5000)
__global__ void k_cbhist(const float* __restrict__ node_emb, const float* __restrict__ enc_b,
                     const float* __restrict__ w_ih, const float* __restrict__ b_ih,
                     const float* __restrict__ b_hh,
                     const float* __restrict__ enc_w, const float* __restrict__ filt_w,
                     const float* __restrict__ filt_b, const float* __restrict__ dec_w,
                     const float* __restrict__ dec_b,
                     float* __restrict__ CB, float* __restrict__ A,
                     float* __restrict__ W2, float* __restrict__ b2,
                     const int* __restrict__ ei, const float* __restrict__ ew,
                     int* cnt_f, int* cnt_b, float* deg_f, float* deg_b) {
    int bid = blockIdx.x;
    if (bid < 3750) {            // CB
        int id = bid * 256 + threadIdx.x;
        int n = id / 96, g = id % 96;
        float s = b_ih[g] + (g < 2*HH ? b_hh[g] : 0.f);
        const float* ne = node_emb + (size_t)n * HH;
        #pragma unroll
        for (int h = 0; h < HH; h++) s += (enc_b[h] + ne[h]) * w_ih[g*HH + h];
        CB[id] = s;
    } else if (bid == 3750) {    // prep
        for (int i = threadIdx.x; i < 96 + 160*12 + 12; i += blockDim.x) {
            if (i < 96) {
                float s = 0.f;
                for (int h = 0; h < HH; h++) s += enc_w[h] * w_ih[i*HH + h];
                A[i] = s;
            } else if (i < 96 + 1920) {
                int j = i - 96; int c = j / 12, o = j % 12;
                float s = 0.f;
                for (int h = 0; h < HH; h++) s += filt_w[c*HH + h] * dec_w[h*12 + o];
                W2[j] = s;
            } else {
                int o = i - 2016;
                float s = dec_b[o];
                for (int h = 0; h < HH; h++) s += filt_b[h] * dec_w[h*12 + o];
                b2[o] = s;
            }
        }
    } else {                     // hist
        int e = (bid - 3751) * 256 + threadIdx.x;
        int s = ei[e], t = ei[EE + e];
        float w = ew[e];
        atomicAdd(&cnt_f[t], 1); atomicAdd(&deg_f[t], w);
        atomicAdd(&cnt_b[s], 1); atomicAdd(&deg_b[s], w);
    }
}

// ---- single-block exclusive scan (2 blocks: fwd / bwd) + inv-degree
__global__ void k_scan(const int* __restrict__ cnt_f, const float* __restrict__ deg_f,
                       int* off_f, int* cur_f, float* inv_f,
                       const int* __restrict__ cnt_b, const float* __restrict__ deg_b,
                       int* off_b, int* cur_b, float* inv_b) {
    const int* cnt; const float* deg; int* off; int* cur; float* inv;
    if (blockIdx.x == 0) { cnt = cnt_f; deg = deg_f; off = off_f; cur = cur_f; inv = inv_f; }
    else                 { cnt = cnt_b; deg = deg_b; off = off_b; cur = cur_b; inv = inv_b; }
    __shared__ int part[1024];
    int t = threadIdx.x;
    const int CH = (NN + 1023) / 1024;  // 10
    int beg = t * CH, end = min(beg + CH, NN);
    int s = 0;
    for (int i = beg; i < end; i++) s += cnt[i];
    part[t] = s;
    __syncthreads();
    for (int d = 1; d < 1024; d <<= 1) {
        int add = (t >= d) ? part[t - d] : 0;
        __syncthreads();
        part[t] += add;
        __syncthreads();
    }
    int run = part[t] - s;  // exclusive base
    for (int i = beg; i < end; i++) {
        off[i] = run; cur[i] = run; run += cnt[i];
        float dv = deg[i];
        inv[i] = dv > 0.f ? 1.0f / dv : 1.0f;
    }
    if (t == 1023) off[NN] = part[1023];
}

// ---- fused GRU over T=12 (+ hidden CSR fill in blocks 0..1249)
// thread = (2 rows, j); WEIGHTS HOISTED TO REGISTERS (12 uint4, loaded from LDS
// once) -> per-step LDS is just 8 b128 h-reads + 2 b32 x-reads + 2 b16 writes.
// x staged in LDS (saves 24 VGPR). Wave owns its 4 rows -> intra-wave exchange
// via ds_write + lgkmcnt(0), no per-step barrier. Output fp16 [n][b][h] only.
__global__ __launch_bounds__(256) void k_gru(const float* __restrict__ x,
                      const float* __restrict__ CB, const float* __restrict__ Ag,
                      const float* __restrict__ w_hh, const float* __restrict__ b_hh,
                      __half* __restrict__ hout16,
                      const int* __restrict__ ei, const float* __restrict__ ew,
                      const float* __restrict__ inv_f, const float* __restrict__ inv_b,
                      int* cur_f, int* cfi, float* cfw,
                      int* cur_b, int* cbi, float* cbw) {
    int tid = threadIdx.x;
    // ---- hidden k_fill: 1250 blocks x 256 threads = EE edges (props run later)
    if (blockIdx.x < EE/256) {
        int e = blockIdx.x * 256 + tid;
        int s = ei[e], t = ei[EE + e]; float w = ew[e];
        int pf = atomicAdd(&cur_f[t], 1); cfi[pf] = s; cfw[pf] = w * inv_f[t];
        int pb = atomicAdd(&cur_b[s], 1); cbi[pb] = t; cbw[pb] = w * inv_b[s];
    }

    __shared__ unsigned swt[96*20];
    __shared__ unsigned sh[16*20];
    __shared__ float sx[16][12];
    int r0 = blockIdx.x * 16;                 // 5000 blocks -> 80000 rows
    for (int i = tid; i < 96*16; i += 256) {   // pack w_hh to fp16
        int g = i >> 4, d = i & 15;
        float2 wv = *(const float2*)(w_hh + g*32 + 2*d);
        swt[g*20 + d] = pkh2(wv.x, wv.y);
    }
    if (tid < 192) {                           // stage x[16 rows][12 t]
        int row = tid & 15, t = tid >> 4;
        int r = r0 + row;
        int b = r / NN, n = r - b * NN;
        sx[row][t] = x[((size_t)b * TT + t) * NN + n];
    }
    __syncthreads();

    const int j = tid & 31, g = tid >> 5;     // g in 0..7
    int rA = r0 + g, rB = r0 + g + 8;
    int bA = rA / NN, nA = rA - bA * NN;
    int bB = rB / NN, nB = rB - bB * NN;

    const float* cA = CB + (size_t)nA * 96;
    const float* cBp = CB + (size_t)nB * 96;
    float cbRA = cA[j],  cbZA = cA[32+j],  cbNA = cA[64+j];
    float cbRB = cBp[j], cbZB = cBp[32+j], cbNB = cBp[64+j];
    float bn0 = b_hh[64+j];
    float aR = Ag[j], aZ = Ag[32+j], aN = Ag[64+j];

    // hoist weights LDS -> registers (loop-invariant)
    const uint4* wRp = (const uint4*)(swt + j*20);
    const uint4* wZp = (const uint4*)(swt + (32+j)*20);
    const uint4* wNp = (const uint4*)(swt + (64+j)*20);
    uint4 wr0 = wRp[0], wr1 = wRp[1], wr2 = wRp[2], wr3 = wRp[3];
    uint4 wz0 = wZp[0], wz1 = wZp[1], wz2 = wZp[2], wz3 = wZp[3];
    uint4 wn0 = wNp[0], wn1 = wNp[1], wn2 = wNp[2], wn3 = wNp[3];

    __half* shh = (__half*)sh;
    float ownA, ownB;
    {   // t = 0: h = 0
        float x0A = sx[g][0], x0B = sx[g+8][0];
        float rrA = sigm(fmaf(x0A, aR, cbRA));
        float zzA = sigm(fmaf(x0A, aZ, cbZA));
        float nvA = tanh_fast(fmaf(x0A, aN, cbNA) + rrA * bn0);
        ownA = (1.f - zzA) * nvA;
        float rrB = sigm(fmaf(x0B, aR, cbRB));
        float zzB = sigm(fmaf(x0B, aZ, cbZB));
        float nvB = tanh_fast(fmaf(x0B, aN, cbNB) + rrB * bn0);
        ownB = (1.f - zzB) * nvB;
    }
    shh[g*40 + j]     = __float2half_rn(ownA);
    shh[(g+8)*40 + j] = __float2half_rn(ownB);

    const uint4* hAp = (const uint4*)(sh + g*20);
    const uint4* hBp = (const uint4*)(sh + (g+8)*20);

    #pragma unroll 1
    for (int t = 1; t < TT; t++) {
        asm volatile("s_waitcnt lgkmcnt(0)" ::: "memory");
        uint4 ha0 = hAp[0], ha1 = hAp[1], ha2 = hAp[2], ha3 = hAp[3];
        uint4 hb0 = hBp[0], hb1 = hBp[1], hb2 = hBp[2], hb3 = hBp[3];
        float xtA = sx[g][t], xtB = sx[g+8][t];

        float pRA = 0.f, qRA = 0.f, pZA = 0.f, qZA = 0.f, pNA = bn0, qNA = 0.f;
        D16(pRA, qRA, wr0,wr1,wr2,wr3, ha0,ha1,ha2,ha3);
        D16(pZA, qZA, wz0,wz1,wz2,wz3, ha0,ha1,ha2,ha3);
        D16(pNA, qNA, wn0,wn1,wn2,wn3, ha0,ha1,ha2,ha3);
        float pRB = 0.f, qRB = 0.f, pZB = 0.f, qZB = 0.f, pNB = bn0, qNB = 0.f;
        D16(pRB, qRB, wr0,wr1,wr2,wr3, hb0,hb1,hb2,hb3);
        D16(pZB, qZB, wz0,wz1,wz2,wz3, hb0,hb1,hb2,hb3);
        D16(pNB, qNB, wn0,wn1,wn2,wn3, hb0,hb1,hb2,hb3);

        float rrA = sigm(fmaf(xtA, aR, cbRA) + pRA + qRA);
        float zzA = sigm(fmaf(xtA, aZ, cbZA) + pZA + qZA);
        float nvA = tanh_fast(fmaf(xtA, aN, cbNA) + rrA * (pNA + qNA));
        ownA = (1.f - zzA) * nvA + zzA * ownA;
        float rrB = sigm(fmaf(xtB, aR, cbRB) + pRB + qRB);
        float zzB = sigm(fmaf(xtB, aZ, cbZB) + pZB + qZB);
        float nvB = tanh_fast(fmaf(xtB, aN, cbNB) + rrB * (pNB + qNB));
        ownB = (1.f - zzB) * nvB + zzB * ownB;
        if (t < TT-1) {
            shh[g*40 + j]     = __float2half_rn(ownA);
            shh[(g+8)*40 + j] = __float2half_rn(ownB);
        }
    }
    hout16[((size_t)nA * BB + bA) * HH + j] = __float2half(ownA);
    hout16[((size_t)nB * BB + bB) * HH + j] = __float2half(ownB);
}

// ---- diffusion hop: wave = (node, dir); lane handles halves 4l..4l+3
// Per edge: ONE dwordx2 per lane (512B/wave, coalesced), fp32 accum, 8-edge
// unroll (8 gathers in flight). fp16 in / fp16 out. Weights pre-scaled.
__global__ __launch_bounds__(256) void k_prop(
        const __half* __restrict__ xF, const __half* __restrict__ xB,
        __half* __restrict__ yF16, __half* __restrict__ yB16,
        const int* __restrict__ offF, const int* __restrict__ idxF, const float* __restrict__ wF,
        const int* __restrict__ offB, const int* __restrict__ idxB, const float* __restrict__ wB) {
    int wid = threadIdx.x >> 6;         // 0..3
    int l   = threadIdx.x & 63;
    int nd = blockIdx.x * 4 + wid;      // 5000 blocks -> 20000 = NN*2
    int n = nd >> 1, dir = nd & 1;
    const unsigned* xu = (const unsigned*)(dir ? xB : xF);
    const int* off = dir ? offB : offF;
    const int* idx = dir ? idxB : idxF;
    const float* w = dir ? wB : wF;

    int e0 = off[n], e1 = off[n+1];
    float a0 = 0.f, a1 = 0.f, a2 = 0.f, a3 = 0.f;
    int e = e0;
    for (; e + 8 <= e1; e += 8) {
        int   s0 = idx[e],   s1 = idx[e+1], s2 = idx[e+2], s3 = idx[e+3];
        int   s4 = idx[e+4], s5 = idx[e+5], s6 = idx[e+6], s7 = idx[e+7];
        float w0 = w[e],     w1 = w[e+1],   w2 = w[e+2],   w3 = w[e+3];
        float w4 = w[e+4],   w5 = w[e+5],   w6 = w[e+6],   w7 = w[e+7];
        uint2 u0 = *(const uint2*)(xu + ((size_t)s0 << 7) + 2*l);
        uint2 u1 = *(const uint2*)(xu + ((size_t)s1 << 7) + 2*l);
        uint2 u2 = *(const uint2*)(xu + ((size_t)s2 << 7) + 2*l);
        uint2 u3 = *(const uint2*)(xu + ((size_t)s3 << 7) + 2*l);
        uint2 u4 = *(const uint2*)(xu + ((size_t)s4 << 7) + 2*l);
        uint2 u5 = *(const uint2*)(xu + ((size_t)s5 << 7) + 2*l);
        uint2 u6 = *(const uint2*)(xu + ((size_t)s6 << 7) + 2*l);
        uint2 u7 = *(const uint2*)(xu + ((size_t)s7 << 7) + 2*l);
        float2 f;
        f = uph2(u0.x); a0 = fmaf(w0, f.x, a0); a1 = fmaf(w0, f.y, a1);
        f = uph2(u0.y); a2 = fmaf(w0, f.x, a2); a3 = fmaf(w0, f.y, a3);
        f = uph2(u1.x); a0 = fmaf(w1, f.x, a0); a1 = fmaf(w1, f.y, a1);
        f = uph2(u1.y); a2 = fmaf(w1, f.x, a2); a3 = fmaf(w1, f.y, a3);
        f = uph2(u2.x); a0 = fmaf(w2, f.x, a0); a1 = fmaf(w2, f.y, a1);
        f = uph2(u2.y); a2 = fmaf(w2, f.x, a2); a3 = fmaf(w2, f.y, a3);
        f = uph2(u3.x); a0 = fmaf(w3, f.x, a0); a1 = fmaf(w3, f.y, a1);
        f = uph2(u3.y); a2 = fmaf(w3, f.x, a2); a3 = fmaf(w3, f.y, a3);
        f = uph2(u4.x); a0 = fmaf(w4, f.x, a0); a1 = fmaf(w4, f.y, a1);
        f = uph2(u4.y); a2 = fmaf(w4, f.x, a2); a3 = fmaf(w4, f.y, a3);
        f = uph2(u5.x); a0 = fmaf(w5, f.x, a0); a1 = fmaf(w5, f.y, a1);
        f = uph2(u5.y); a2 = fmaf(w5, f.x, a2); a3 = fmaf(w5, f.y, a3);
        f = uph2(u6.x); a0 = fmaf(w6, f.x, a0); a1 = fmaf(w6, f.y, a1);
        f = uph2(u6.y); a2 = fmaf(w6, f.x, a2); a3 = fmaf(w6, f.y, a3);
        f = uph2(u7.x); a0 = fmaf(w7, f.x, a0); a1 = fmaf(w7, f.y, a1);
        f = uph2(u7.y); a2 = fmaf(w7, f.x, a2); a3 = fmaf(w7, f.y, a3);
    }
    for (; e + 2 <= e1; e += 2) {
        int s0 = idx[e], s1 = idx[e+1];
        float w0 = w[e], w1 = w[e+1];
        uint2 u0 = *(const uint2*)(xu + ((size_t)s0 << 7) + 2*l);
        uint2 u1 = *(const uint2*)(xu + ((size_t)s1 << 7) + 2*l);
        float2 f;
        f = uph2(u0.x); a0 = fmaf(w0, f.x, a0); a1 = fmaf(w0, f.y, a1);
        f = uph2(u0.y); a2 = fmaf(w0, f.x, a2); a3 = fmaf(w0, f.y, a3);
        f = uph2(u1.x); a0 = fmaf(w1, f.x, a0); a1 = fmaf(w1, f.y, a1);
        f = uph2(u1.y); a2 = fmaf(w1, f.x, a2); a3 = fmaf(w1, f.y, a3);
    }
    if (e < e1) {
        int s0 = idx[e]; float w0 = w[e];
        uint2 u0 = *(const uint2*)(xu + ((size_t)s0 << 7) + 2*l);
        float2 f;
        f = uph2(u0.x); a0 = fmaf(w0, f.x, a0); a1 = fmaf(w0, f.y, a1);
        f = uph2(u0.y); a2 = fmaf(w0, f.x, a2); a3 = fmaf(w0, f.y, a3);
    }
    unsigned* yh = (unsigned*)(dir ? yB16 : yF16);
    uint2 oh; oh.x = pkh2(a0, a1); oh.y = pkh2(a2, a3);
    *(uint2*)(yh + ((size_t)n << 7) + 2*l) = oh;
}

// ---- fused decoder (fp16 pieces): out[b,t,n] = b2[t] + sum piece_pi[n,b,c]*W2[pi*32+c,t]
__global__ __launch_bounds__(256) void k_dec(const __half* __restrict__ p0,
                     const __half* __restrict__ p1, const __half* __restrict__ p2,
                     const __half* __restrict__ p3, const __half* __restrict__ p4,
                     const float* __restrict__ W2, const float* __restrict__ b2,
                     float* __restrict__ out) {
    __shared__ float sW[1920];
    __shared__ float sb[12];
    int tid = threadIdx.x;
    for (int i = tid; i < 1920; i += 256) sW[i] = W2[i];
    if (tid < 12) sb[tid] = b2[tid];
    __syncthreads();
    int r = blockIdx.x * 256 + tid;
    if (r >= BB*NN) return;
    int b = r / NN, n = r - b*NN;
    size_t base = ((size_t)n * BB + b) * HH;
    float a[12];
    #pragma unroll
    for (int o = 0; o < 12; o++) a[o] = sb[o];
    const __half* ps[5] = {p0, p1, p2, p3, p4};
    #pragma unroll
    for (int pi = 0; pi < 5; pi++) {
        const uint4* pp = (const uint4*)(ps[pi] + base);
        #pragma unroll
        for (int q = 0; q < 4; q++) {
            uint4 v = pp[q];
            float2 f0 = uph2(v.x), f1 = uph2(v.y), f2 = uph2(v.z), f3 = uph2(v.w);
            float pv[8] = {f0.x, f0.y, f1.x, f1.y, f2.x, f2.y, f3.x, f3.y};
            #pragma unroll
            for (int k = 0; k < 8; k++) {
                const float* wrow = sW + (pi*32 + q*8 + k) * 12;
                #pragma unroll
                for (int o = 0; o < 12; o++) a[o] = fmaf(pv[k], wrow[o], a[o]);
            }
        }
    }
    #pragma unroll
    for (int t = 0; t < HOR; t++)
        out[((size_t)(b*HOR + t))*NN + n] = a[t];
}

extern "C" void kernel_launch(void* const* d_in, const int* in_sizes, int n_in,
                              void* d_out, int out_size, void* d_ws, size_t ws_size,
                              hipStream_t stream) {
    const float* x      = (const float*)d_in[0];
    const int*   ei     = (const int*)d_in[1];
    const float* ew     = (const float*)d_in[2];
    const float* enc_w  = (const float*)d_in[3];
    const float* enc_b  = (const float*)d_in[4];
    const float* nemb   = (const float*)d_in[5];
    const float* w_ih   = (const float*)d_in[6];
    const float* w_hh   = (const float*)d_in[7];
    const float* b_ih   = (const float*)d_in[8];
    const float* b_hh   = (const float*)d_in[9];
    const float* filt_w = (const float*)d_in[10];
    const float* filt_b = (const float*)d_in[11];
    const float* dec_w  = (const float*)d_in[12];
    const float* dec_b  = (const float*)d_in[13];
    float* out = (float*)d_out;

    char* p = (char*)d_ws;
    auto alloc = [&](size_t bytes) -> char* {
        char* q = p; p += (bytes + 255) & ~(size_t)255; return q;
    };
    // zero-region (single memset): cnt_f, cnt_b, deg_f, deg_b
    char* zero_base = p;
    int*   cnt_f = (int*)  alloc((size_t)NN*4);
    int*   cnt_b = (int*)  alloc((size_t)NN*4);
    float* deg_f = (float*)alloc((size_t)NN*4);
    float* deg_b = (float*)alloc((size_t)NN*4);
    size_t zero_bytes = (size_t)(p - zero_base);

    const size_t SROW = (size_t)BB*NN*HH;
    __half* h16    = (__half*)alloc(SROW*2);
    __half* a16    = (__half*)alloc(SROW*2);
    __half* b16    = (__half*)alloc(SROW*2);
    __half* c16    = (__half*)alloc(SROW*2);
    __half* d16    = (__half*)alloc(SROW*2);
    float* CB     = (float*)alloc((size_t)NN*96*4);
    float* A      = (float*)alloc(96*4);
    float* W2     = (float*)alloc(1920*4);
    float* b2     = (float*)alloc(12*4);
    float* inv_f  = (float*)alloc((size_t)NN*4);
    float* inv_b  = (float*)alloc((size_t)NN*4);
    int*   off_f  = (int*)  alloc((size_t)(NN+1)*4);
    int*   off_b  = (int*)  alloc((size_t)(NN+1)*4);
    int*   cur_f  = (int*)  alloc((size_t)NN*4);
    int*   cur_b  = (int*)  alloc((size_t)NN*4);
    int*   cfi    = (int*)  alloc((size_t)EE*4);
    float* cfw    = (float*)alloc((size_t)EE*4);
    int*   cbi    = (int*)  alloc((size_t)EE*4);
    float* cbw    = (float*)alloc((size_t)EE*4);

    hipMemsetAsync(zero_base, 0, zero_bytes, stream);

    k_cbhist<<<5001, 256, 0, stream>>>(nemb, enc_b, w_ih, b_ih, b_hh,
                                       enc_w, filt_w, filt_b, dec_w, dec_b,
                                       CB, A, W2, b2,
                                       ei, ew, cnt_f, cnt_b, deg_f, deg_b);
    k_scan<<<2, 1024, 0, stream>>>(cnt_f, deg_f, off_f, cur_f, inv_f,
                                   cnt_b, deg_b, off_b, cur_b, inv_b);

    // k_fill is fused into k_gru's first 1250 blocks (props run after gru)
    k_gru<<<5000, 256, 0, stream>>>(x, CB, A, w_hh, b_hh, h16,
                                    ei, ew, inv_f, inv_b,
                                    cur_f, cfi, cfw, cur_b, cbi, cbw);

    k_prop<<<5000, 256, 0, stream>>>(h16, h16, a16, c16,
                                     off_f, cfi, cfw, off_b, cbi, cbw);
    k_prop<<<5000, 256, 0, stream>>>(a16, c16, b16, d16,
                                     off_f, cfi, cfw, off_b, cbi, cbw);

    k_dec<<<(BB*NN + 255)/256, 256, 0, stream>>>(h16, a16, b16, c16, d16, W2, b2, out);
}

// Round 9
// 272.753 us; speedup vs baseline: 8.9120x; 1.1006x over previous
//
#include <hip/hip_runtime.h>
#include <hip/hip_fp16.h>

#define BB 8
#define TT 12
#define NN 10000
#define HH 32
#define EE 320000
#define HOR 12

static __device__ __forceinline__ float sigm(float x) {
    return __builtin_amdgcn_rcpf(1.0f + __expf(-x));
}
static __device__ __forceinline__ float tanh_fast(float x) {
    return 1.0f - 2.0f * __builtin_amdgcn_rcpf(1.0f + __expf(2.0f * x));
}
static __device__ __forceinline__ float2 uph2(unsigned u) {
    __half2 h = *(__half2*)&u;
    return __half22float2(h);
}
static __device__ __forceinline__ unsigned pkh2(float a, float b) {
    __half2 h = __floats2half2_rn(a, b);
    return *(unsigned*)&h;
}
typedef _Float16 h2_t __attribute__((ext_vector_type(2)));
static __device__ __forceinline__ float dot2(unsigned a, unsigned b, float c) {
    return __builtin_amdgcn_fdot2(__builtin_bit_cast(h2_t, a),
                                  __builtin_bit_cast(h2_t, b), c, false);
}

// 16 dot2 (= 32 MAC) with two chains
#define D16(P, Q, W0,W1,W2,W3, H0,H1,H2,H3) \
    P = dot2(W0.x,H0.x,P); Q = dot2(W0.y,H0.y,Q); P = dot2(W0.z,H0.z,P); Q = dot2(W0.w,H0.w,Q); \
    P = dot2(W1.x,H1.x,P); Q = dot2(W1.y,H1.y,Q); P = dot2(W1.z,H1.z,P); Q = dot2(W1.w,H1.w,Q); \
    P = dot2(W2.x,H2.x,P); Q = dot2(W2.y,H2.y,Q); P = dot2(W2.z,H2.z,P); Q = dot2(W2.w,H2.w,Q); \
    P = dot2(W3.x,H3.x,P); Q = dot2(W3.y,H3.y,Q); P = dot2(W3.z,H3.z,P); Q = dot2(W3.w,H3.w,Q);

// opaque pin: forces the 4 dwords into VGPRs; volatile asm cannot be
// rematerialized, so the compiler can't sink the LDS loads back into the loop
#define PIN4(u) asm volatile("" : "+v"(u.x), "+v"(u.y), "+v"(u.z), "+v"(u.w))

// ---- fused: CB precompute (blocks 0..3749), tiny prep (3750), edge count histogram (3751..5000)
__global__ void k_cbhist(const float* __restrict__ node_emb, const float* __restrict__ enc_b,
                     const float* __restrict__ w_ih, const float* __restrict__ b_ih,
                     const float* __restrict__ b_hh,
                     const float* __restrict__ enc_w, const float* __restrict__ filt_w,
                     const float* __restrict__ filt_b, const float* __restrict__ dec_w,
                     const float* __restrict__ dec_b,
                     float* __restrict__ CB, float* __restrict__ A,
                     float* __restrict__ W2, float* __restrict__ b2,
                     const int* __restrict__ ei,
                     int* cnt_f, int* cnt_b) {
    int bid = blockIdx.x;
    if (bid < 3750) {            // CB
        int id = bid * 256 + threadIdx.x;
        int n = id / 96, g = id % 96;
        float s = b_ih[g] + (g < 2*HH ? b_hh[g] : 0.f);
        const float* ne = node_emb + (size_t)n * HH;
        #pragma unroll
        for (int h = 0; h < HH; h++) s += (enc_b[h] + ne[h]) * w_ih[g*HH + h];
        CB[id] = s;
    } else if (bid == 3750) {    // prep
        for (int i = threadIdx.x; i < 96 + 160*12 + 12; i += blockDim.x) {
            if (i < 96) {
                float s = 0.f;
                for (int h = 0; h < HH; h++) s += enc_w[h] * w_ih[i*HH + h];
                A[i] = s;
            } else if (i < 96 + 1920) {
                int j = i - 96; int c = j / 12, o = j % 12;
                float s = 0.f;
                for (int h = 0; h < HH; h++) s += filt_w[c*HH + h] * dec_w[h*12 + o];
                W2[j] = s;
            } else {
                int o = i - 2016;
                float s = dec_b[o];
                for (int h = 0; h < HH; h++) s += filt_b[h] * dec_w[h*12 + o];
                b2[o] = s;
            }
        }
    } else {                     // count histogram only (normalization moved into k_prop)
        int e = (bid - 3751) * 256 + threadIdx.x;
        int s = ei[e], t = ei[EE + e];
        atomicAdd(&cnt_f[t], 1);
        atomicAdd(&cnt_b[s], 1);
    }
}

// ---- single-block exclusive scan (2 blocks: fwd / bwd)
__global__ void k_scan(const int* __restrict__ cnt_f, int* off_f, int* cur_f,
                       const int* __restrict__ cnt_b, int* off_b, int* cur_b) {
    const int* cnt; int* off; int* cur;
    if (blockIdx.x == 0) { cnt = cnt_f; off = off_f; cur = cur_f; }
    else                 { cnt = cnt_b; off = off_b; cur = cur_b; }
    __shared__ int part[1024];
    int t = threadIdx.x;
    const int CH = (NN + 1023) / 1024;  // 10
    int beg = t * CH, end = min(beg + CH, NN);
    int s = 0;
    for (int i = beg; i < end; i++) s += cnt[i];
    part[t] = s;
    __syncthreads();
    for (int d = 1; d < 1024; d <<= 1) {
        int add = (t >= d) ? part[t - d] : 0;
        __syncthreads();
        part[t] += add;
        __syncthreads();
    }
    int run = part[t] - s;  // exclusive base
    for (int i = beg; i < end; i++) {
        off[i] = run; cur[i] = run; run += cnt[i];
    }
    if (t == 1023) off[NN] = part[1023];
}

// ---- scatter edges into CSR buckets (raw weights; prop normalizes)
__global__ void k_fill(const int* __restrict__ ei, const float* __restrict__ ew,
                       int* cur_f, int* csr_f_idx, float* csr_f_w,
                       int* cur_b, int* csr_b_idx, float* csr_b_w) {
    int e = blockIdx.x * blockDim.x + threadIdx.x;  // EE exactly
    int s = ei[e], t = ei[EE + e]; float w = ew[e];
    int pf = atomicAdd(&cur_f[t], 1); csr_f_idx[pf] = s; csr_f_w[pf] = w;
    int pb = atomicAdd(&cur_b[s], 1); csr_b_idx[pb] = t; csr_b_w[pb] = w;
}

// ---- fused GRU over T=12, thread = (2 rows, j); fp16 weights PINNED in VGPRs
// Block 256 = 8 groups x 32 j. Wave owns its 4 rows -> intra-wave exchange via
// ds_write + lgkmcnt(0), no per-step barrier. Per-step LDS: 8 b128 h-reads +
// 2 b32 x-reads + 2 b16 writes. Output fp16 [n][b][h].
__global__ __launch_bounds__(256) void k_gru(const float* __restrict__ x,
                      const float* __restrict__ CB, const float* __restrict__ Ag,
                      const float* __restrict__ w_hh, const float* __restrict__ b_hh,
                      __half* __restrict__ hout16) {
    __shared__ unsigned swt[96*20];
    __shared__ unsigned sh[16*20];
    __shared__ float sx[16][12];
    int tid = threadIdx.x;
    int r0 = blockIdx.x * 16;                 // 5000 blocks -> 80000 rows
    for (int i = tid; i < 96*16; i += 256) {   // pack w_hh to fp16
        int g = i >> 4, d = i & 15;
        float2 wv = *(const float2*)(w_hh + g*32 + 2*d);
        swt[g*20 + d] = pkh2(wv.x, wv.y);
    }
    if (tid < 192) {                           // stage x[16 rows][12 t]
        int row = tid & 15, t = tid >> 4;
        int r = r0 + row;
        int b = r / NN, n = r - b * NN;
        sx[row][t] = x[((size_t)b * TT + t) * NN + n];
    }
    __syncthreads();

    const int j = tid & 31, g = tid >> 5;     // g in 0..7
    int rA = r0 + g, rB = r0 + g + 8;
    int bA = rA / NN, nA = rA - bA * NN;
    int bB = rB / NN, nB = rB - bB * NN;

    const float* cA = CB + (size_t)nA * 96;
    const float* cBp = CB + (size_t)nB * 96;
    float cbRA = cA[j],  cbZA = cA[32+j],  cbNA = cA[64+j];
    float cbRB = cBp[j], cbZB = cBp[32+j], cbNB = cBp[64+j];
    float bn0 = b_hh[64+j];
    float aR = Ag[j], aZ = Ag[32+j], aN = Ag[64+j];

    // hoist weights LDS -> registers, then PIN so they can't be rematerialized
    const uint4* wRp = (const uint4*)(swt + j*20);
    const uint4* wZp = (const uint4*)(swt + (32+j)*20);
    const uint4* wNp = (const uint4*)(swt + (64+j)*20);
    uint4 wr0 = wRp[0], wr1 = wRp[1], wr2 = wRp[2], wr3 = wRp[3];
    uint4 wz0 = wZp[0], wz1 = wZp[1], wz2 = wZp[2], wz3 = wZp[3];
    uint4 wn0 = wNp[0], wn1 = wNp[1], wn2 = wNp[2], wn3 = wNp[3];
    PIN4(wr0); PIN4(wr1); PIN4(wr2); PIN4(wr3);
    PIN4(wz0); PIN4(wz1); PIN4(wz2); PIN4(wz3);
    PIN4(wn0); PIN4(wn1); PIN4(wn2); PIN4(wn3);

    __half* shh = (__half*)sh;
    float ownA, ownB;
    {   // t = 0: h = 0
        float x0A = sx[g][0], x0B = sx[g+8][0];
        float rrA = sigm(fmaf(x0A, aR, cbRA));
        float zzA = sigm(fmaf(x0A, aZ, cbZA));
        float nvA = tanh_fast(fmaf(x0A, aN, cbNA) + rrA * bn0);
        ownA = (1.f - zzA) * nvA;
        float rrB = sigm(fmaf(x0B, aR, cbRB));
        float zzB = sigm(fmaf(x0B, aZ, cbZB));
        float nvB = tanh_fast(fmaf(x0B, aN, cbNB) + rrB * bn0);
        ownB = (1.f - zzB) * nvB;
    }
    shh[g*40 + j]     = __float2half_rn(ownA);
    shh[(g+8)*40 + j] = __float2half_rn(ownB);

    const uint4* hAp = (const uint4*)(sh + g*20);
    const uint4* hBp = (const uint4*)(sh + (g+8)*20);

    #pragma unroll 1
    for (int t = 1; t < TT; t++) {
        asm volatile("s_waitcnt lgkmcnt(0)" ::: "memory");
        uint4 ha0 = hAp[0], ha1 = hAp[1], ha2 = hAp[2], ha3 = hAp[3];
        uint4 hb0 = hBp[0], hb1 = hBp[1], hb2 = hBp[2], hb3 = hBp[3];
        float xtA = sx[g][t], xtB = sx[g+8][t];

        float pRA = 0.f, qRA = 0.f, pZA = 0.f, qZA = 0.f, pNA = bn0, qNA = 0.f;
        D16(pRA, qRA, wr0,wr1,wr2,wr3, ha0,ha1,ha2,ha3);
        D16(pZA, qZA, wz0,wz1,wz2,wz3, ha0,ha1,ha2,ha3);
        D16(pNA, qNA, wn0,wn1,wn2,wn3, ha0,ha1,ha2,ha3);
        float pRB = 0.f, qRB = 0.f, pZB = 0.f, qZB = 0.f, pNB = bn0, qNB = 0.f;
        D16(pRB, qRB, wr0,wr1,wr2,wr3, hb0,hb1,hb2,hb3);
        D16(pZB, qZB, wz0,wz1,wz2,wz3, hb0,hb1,hb2,hb3);
        D16(pNB, qNB, wn0,wn1,wn2,wn3, hb0,hb1,hb2,hb3);

        float rrA = sigm(fmaf(xtA, aR, cbRA) + pRA + qRA);
        float zzA = sigm(fmaf(xtA, aZ, cbZA) + pZA + qZA);
        float nvA = tanh_fast(fmaf(xtA, aN, cbNA) + rrA * (pNA + qNA));
        ownA = (1.f - zzA) * nvA + zzA * ownA;
        float rrB = sigm(fmaf(xtB, aR, cbRB) + pRB + qRB);
        float zzB = sigm(fmaf(xtB, aZ, cbZB) + pZB + qZB);
        float nvB = tanh_fast(fmaf(xtB, aN, cbNB) + rrB * (pNB + qNB));
        ownB = (1.f - zzB) * nvB + zzB * ownB;
        if (t < TT-1) {
            shh[g*40 + j]     = __float2half_rn(ownA);
            shh[(g+8)*40 + j] = __float2half_rn(ownB);
        }
    }
    hout16[((size_t)nA * BB + bA) * HH + j] = __float2half(ownA);
    hout16[((size_t)nB * BB + bB) * HH + j] = __float2half(ownB);
}

// ---- diffusion hop: wave = (node, dir); normalization computed in-kernel:
// acc = (sum_e w[e] * x[idx[e]]) * rcp(sum_e w[e])  (= reference's deg scaling,
// since both directions normalize by the CSR-owning node's weighted degree).
__global__ __launch_bounds__(256) void k_prop(
        const __half* __restrict__ xF, const __half* __restrict__ xB,
        __half* __restrict__ yF16, __half* __restrict__ yB16,
        const int* __restrict__ offF, const int* __restrict__ idxF, const float* __restrict__ wF,
        const int* __restrict__ offB, const int* __restrict__ idxB, const float* __restrict__ wB) {
    int wid = threadIdx.x >> 6;         // 0..3
    int l   = threadIdx.x & 63;
    int nd = blockIdx.x * 4 + wid;      // 5000 blocks -> 20000 = NN*2
    int n = nd >> 1, dir = nd & 1;
    const unsigned* xu = (const unsigned*)(dir ? xB : xF);
    const int* off = dir ? offB : offF;
    const int* idx = dir ? idxB : idxF;
    const float* w = dir ? wB : wF;

    int e0 = off[n], e1 = off[n+1];
    float a0 = 0.f, a1 = 0.f, a2 = 0.f, a3 = 0.f, ws = 0.f;
    int e = e0;
    for (; e + 8 <= e1; e += 8) {
        int   s0 = idx[e],   s1 = idx[e+1], s2 = idx[e+2], s3 = idx[e+3];
        int   s4 = idx[e+4], s5 = idx[e+5], s6 = idx[e+6], s7 = idx[e+7];
        float w0 = w[e],     w1 = w[e+1],   w2 = w[e+2],   w3 = w[e+3];
        float w4 = w[e+4],   w5 = w[e+5],   w6 = w[e+6],   w7 = w[e+7];
        uint2 u0 = *(const uint2*)(xu + ((size_t)s0 << 7) + 2*l);
        uint2 u1 = *(const uint2*)(xu + ((size_t)s1 << 7) + 2*l);
        uint2 u2 = *(const uint2*)(xu + ((size_t)s2 << 7) + 2*l);
        uint2 u3 = *(const uint2*)(xu + ((size_t)s3 << 7) + 2*l);
        uint2 u4 = *(const uint2*)(xu + ((size_t)s4 << 7) + 2*l);
        uint2 u5 = *(const uint2*)(xu + ((size_t)s5 << 7) + 2*l);
        uint2 u6 = *(const uint2*)(xu + ((size_t)s6 << 7) + 2*l);
        uint2 u7 = *(const uint2*)(xu + ((size_t)s7 << 7) + 2*l);
        ws += ((w0 + w1) + (w2 + w3)) + ((w4 + w5) + (w6 + w7));
        float2 f;
        f = uph2(u0.x); a0 = fmaf(w0, f.x, a0); a1 = fmaf(w0, f.y, a1);
        f = uph2(u0.y); a2 = fmaf(w0, f.x, a2); a3 = fmaf(w0, f.y, a3);
        f = uph2(u1.x); a0 = fmaf(w1, f.x, a0); a1 = fmaf(w1, f.y, a1);
        f = uph2(u1.y); a2 = fmaf(w1, f.x, a2); a3 = fmaf(w1, f.y, a3);
        f = uph2(u2.x); a0 = fmaf(w2, f.x, a0); a1 = fmaf(w2, f.y, a1);
        f = uph2(u2.y); a2 = fmaf(w2, f.x, a2); a3 = fmaf(w2, f.y, a3);
        f = uph2(u3.x); a0 = fmaf(w3, f.x, a0); a1 = fmaf(w3, f.y, a1);
        f = uph2(u3.y); a2 = fmaf(w3, f.x, a2); a3 = fmaf(w3, f.y, a3);
        f = uph2(u4.x); a0 = fmaf(w4, f.x, a0); a1 = fmaf(w4, f.y, a1);
        f = uph2(u4.y); a2 = fmaf(w4, f.x, a2); a3 = fmaf(w4, f.y, a3);
        f = uph2(u5.x); a0 = fmaf(w5, f.x, a0); a1 = fmaf(w5, f.y, a1);
        f = uph2(u5.y); a2 = fmaf(w5, f.x, a2); a3 = fmaf(w5, f.y, a3);
        f = uph2(u6.x); a0 = fmaf(w6, f.x, a0); a1 = fmaf(w6, f.y, a1);
        f = uph2(u6.y); a2 = fmaf(w6, f.x, a2); a3 = fmaf(w6, f.y, a3);
        f = uph2(u7.x); a0 = fmaf(w7, f.x, a0); a1 = fmaf(w7, f.y, a1);
        f = uph2(u7.y); a2 = fmaf(w7, f.x, a2); a3 = fmaf(w7, f.y, a3);
    }
    for (; e < e1; ++e) {
        int s0 = idx[e]; float w0 = w[e];
        uint2 u0 = *(const uint2*)(xu + ((size_t)s0 << 7) + 2*l);
        ws += w0;
        float2 f;
        f = uph2(u0.x); a0 = fmaf(w0, f.x, a0); a1 = fmaf(w0, f.y, a1);
        f = uph2(u0.y); a2 = fmaf(w0, f.x, a2); a3 = fmaf(w0, f.y, a3);
    }
    float inv = ws > 0.f ? __builtin_amdgcn_rcpf(ws) : 1.0f;
    a0 *= inv; a1 *= inv; a2 *= inv; a3 *= inv;
    unsigned* yh = (unsigned*)(dir ? yB16 : yF16);
    uint2 oh; oh.x = pkh2(a0, a1); oh.y = pkh2(a2, a3);
    *(uint2*)(yh + ((size_t)n << 7) + 2*l) = oh;
}

// ---- fused decoder (fp16 pieces): out[b,t,n] = b2[t] + sum piece_pi[n,b,c]*W2[pi*32+c,t]
__global__ __launch_bounds__(256) void k_dec(const __half* __restrict__ p0,
                     const __half* __restrict__ p1, const __half* __restrict__ p2,
                     const __half* __restrict__ p3, const __half* __restrict__ p4,
                     const float* __restrict__ W2, const float* __restrict__ b2,
                     float* __restrict__ out) {
    __shared__ float sW[1920];
    __shared__ float sb[12];
    int tid = threadIdx.x;
    for (int i = tid; i < 1920; i += 256) sW[i] = W2[i];
    if (tid < 12) sb[tid] = b2[tid];
    __syncthreads();
    int r = blockIdx.x * 256 + tid;
    if (r >= BB*NN) return;
    int b = r / NN, n = r - b*NN;
    size_t base = ((size_t)n * BB + b) * HH;
    float a[12];
    #pragma unroll
    for (int o = 0; o < 12; o++) a[o] = sb[o];
    const __half* ps[5] = {p0, p1, p2, p3, p4};
    #pragma unroll
    for (int pi = 0; pi < 5; pi++) {
        const uint4* pp = (const uint4*)(ps[pi] + base);
        #pragma unroll
        for (int q = 0; q < 4; q++) {
            uint4 v = pp[q];
            float2 f0 = uph2(v.x), f1 = uph2(v.y), f2 = uph2(v.z), f3 = uph2(v.w);
            float pv[8] = {f0.x, f0.y, f1.x, f1.y, f2.x, f2.y, f3.x, f3.y};
            #pragma unroll
            for (int k = 0; k < 8; k++) {
                const float* wrow = sW + (pi*32 + q*8 + k) * 12;
                #pragma unroll
                for (int o = 0; o < 12; o++) a[o] = fmaf(pv[k], wrow[o], a[o]);
            }
        }
    }
    #pragma unroll
    for (int t = 0; t < HOR; t++)
        out[((size_t)(b*HOR + t))*NN + n] = a[t];
}

extern "C" void kernel_launch(void* const* d_in, const int* in_sizes, int n_in,
                              void* d_out, int out_size, void* d_ws, size_t ws_size,
                              hipStream_t stream) {
    const float* x      = (const float*)d_in[0];
    const int*   ei     = (const int*)d_in[1];
    const float* ew     = (const float*)d_in[2];
    const float* enc_w  = (const float*)d_in[3];
    const float* enc_b  = (const float*)d_in[4];
    const float* nemb   = (const float*)d_in[5];
    const float* w_ih   = (const float*)d_in[6];
    const float* w_hh   = (const float*)d_in[7];
    const float* b_ih   = (const float*)d_in[8];
    const float* b_hh   = (const float*)d_in[9];
    const float* filt_w = (const float*)d_in[10];
    const float* filt_b = (const float*)d_in[11];
    const float* dec_w  = (const float*)d_in[12];
    const float* dec_b  = (const float*)d_in[13];
    float* out = (float*)d_out;

    char* p = (char*)d_ws;
    auto alloc = [&](size_t bytes) -> char* {
        char* q = p; p += (bytes + 255) & ~(size_t)255; return q;
    };
    // zero-region (single memset): cnt_f, cnt_b
    char* zero_base = p;
    int*   cnt_f = (int*)  alloc((size_t)NN*4);
    int*   cnt_b = (int*)  alloc((size_t)NN*4);
    size_t zero_bytes = (size_t)(p - zero_base);

    const size_t SROW = (size_t)BB*NN*HH;
    __half* h16    = (__half*)alloc(SROW*2);
    __half* a16    = (__half*)alloc(SROW*2);
    __half* b16    = (__half*)alloc(SROW*2);
    __half* c16    = (__half*)alloc(SROW*2);
    __half* d16    = (__half*)alloc(SROW*2);
    float* CB     = (float*)alloc((size_t)NN*96*4);
    float* A      = (float*)alloc(96*4);
    float* W2     = (float*)alloc(1920*4);
    float* b2     = (float*)alloc(12*4);
    int*   off_f  = (int*)  alloc((size_t)(NN+1)*4);
    int*   off_b  = (int*)  alloc((size_t)(NN+1)*4);
    int*   cur_f  = (int*)  alloc((size_t)NN*4);
    int*   cur_b  = (int*)  alloc((size_t)NN*4);
    int*   cfi    = (int*)  alloc((size_t)EE*4);
    float* cfw    = (float*)alloc((size_t)EE*4);
    int*   cbi    = (int*)  alloc((size_t)EE*4);
    float* cbw    = (float*)alloc((size_t)EE*4);

    hipMemsetAsync(zero_base, 0, zero_bytes, stream);

    k_cbhist<<<5001, 256, 0, stream>>>(nemb, enc_b, w_ih, b_ih, b_hh,
                                       enc_w, filt_w, filt_b, dec_w, dec_b,
                                       CB, A, W2, b2, ei, cnt_f, cnt_b);
    k_scan<<<2, 1024, 0, stream>>>(cnt_f, off_f, cur_f, cnt_b, off_b, cur_b);
    k_fill<<<EE/256, 256, 0, stream>>>(ei, ew, cur_f, cfi, cfw, cur_b, cbi, cbw);

    k_gru<<<5000, 256, 0, stream>>>(x, CB, A, w_hh, b_hh, h16);

    k_prop<<<5000, 256, 0, stream>>>(h16, h16, a16, c16,
                                     off_f, cfi, cfw, off_b, cbi, cbw);
    k_prop<<<5000, 256, 0, stream>>>(a16, c16, b16, d16,
                                     off_f, cfi, cfw, off_b, cbi, cbw);

    k_dec<<<(BB*NN + 255)/256, 256, 0, stream>>>(h16, a16, b16, c16, d16, W2, b2, out);
}

// Round 10
// 231.695 us; speedup vs baseline: 10.4912x; 1.1772x over previous
//
#include <hip/hip_runtime.h>
#include <hip/hip_fp16.h>

#define BB 8
#define TT 12
#define NN 10000
#define HH 32
#define EE 320000
#define HOR 12

static __device__ __forceinline__ float sigm(float x) {
    return __builtin_amdgcn_rcpf(1.0f + __expf(-x));
}
static __device__ __forceinline__ float tanh_fast(float x) {
    return 1.0f - 2.0f * __builtin_amdgcn_rcpf(1.0f + __expf(2.0f * x));
}
static __device__ __forceinline__ float2 uph2(unsigned u) {
    __half2 h = *(__half2*)&u;
    return __half22float2(h);
}
static __device__ __forceinline__ unsigned pkh2(float a, float b) {
    __half2 h = __floats2half2_rn(a, b);
    return *(unsigned*)&h;
}

typedef _Float16 f16x4 __attribute__((ext_vector_type(4)));
typedef float    f32x4 __attribute__((ext_vector_type(4)));

// ---- fused: CB precompute (blocks 0..3749), tiny prep (3750), edge count histogram (3751..5000)
__global__ void k_cbhist(const float* __restrict__ node_emb, const float* __restrict__ enc_b,
                     const float* __restrict__ w_ih, const float* __restrict__ b_ih,
                     const float* __restrict__ b_hh,
                     const float* __restrict__ enc_w, const float* __restrict__ filt_w,
                     const float* __restrict__ filt_b, const float* __restrict__ dec_w,
                     const float* __restrict__ dec_b,
                     float* __restrict__ CB, float* __restrict__ A,
                     float* __restrict__ W2, float* __restrict__ b2,
                     const int* __restrict__ ei,
                     int* cnt_f, int* cnt_b) {
    int bid = blockIdx.x;
    if (bid < 3750) {            // CB
        int id = bid * 256 + threadIdx.x;
        int n = id / 96, g = id % 96;
        float s = b_ih[g] + (g < 2*HH ? b_hh[g] : 0.f);
        const float* ne = node_emb + (size_t)n * HH;
        #pragma unroll
        for (int h = 0; h < HH; h++) s += (enc_b[h] + ne[h]) * w_ih[g*HH + h];
        CB[id] = s;
    } else if (bid == 3750) {    // prep
        for (int i = threadIdx.x; i < 96 + 160*12 + 12; i += blockDim.x) {
            if (i < 96) {
                float s = 0.f;
                for (int h = 0; h < HH; h++) s += enc_w[h] * w_ih[i*HH + h];
                A[i] = s;
            } else if (i < 96 + 1920) {
                int j = i - 96; int c = j / 12, o = j % 12;
                float s = 0.f;
                for (int h = 0; h < HH; h++) s += filt_w[c*HH + h] * dec_w[h*12 + o];
                W2[j] = s;
            } else {
                int o = i - 2016;
                float s = dec_b[o];
                for (int h = 0; h < HH; h++) s += filt_b[h] * dec_w[h*12 + o];
                b2[o] = s;
            }
        }
    } else {                     // count histogram only (normalization lives in k_prop)
        int e = (bid - 3751) * 256 + threadIdx.x;
        int s = ei[e], t = ei[EE + e];
        atomicAdd(&cnt_f[t], 1);
        atomicAdd(&cnt_b[s], 1);
    }
}

// ---- single-block exclusive scan (2 blocks: fwd / bwd)
__global__ void k_scan(const int* __restrict__ cnt_f, int* off_f, int* cur_f,
                       const int* __restrict__ cnt_b, int* off_b, int* cur_b) {
    const int* cnt; int* off; int* cur;
    if (blockIdx.x == 0) { cnt = cnt_f; off = off_f; cur = cur_f; }
    else                 { cnt = cnt_b; off = off_b; cur = cur_b; }
    __shared__ int part[1024];
    int t = threadIdx.x;
    const int CH = (NN + 1023) / 1024;  // 10
    int beg = t * CH, end = min(beg + CH, NN);
    int s = 0;
    for (int i = beg; i < end; i++) s += cnt[i];
    part[t] = s;
    __syncthreads();
    for (int d = 1; d < 1024; d <<= 1) {
        int add = (t >= d) ? part[t - d] : 0;
        __syncthreads();
        part[t] += add;
        __syncthreads();
    }
    int run = part[t] - s;  // exclusive base
    for (int i = beg; i < end; i++) {
        off[i] = run; cur[i] = run; run += cnt[i];
    }
    if (t == 1023) off[NN] = part[1023];
}

// ---- scatter edges into CSR buckets (raw weights; prop normalizes)
__global__ void k_fill(const int* __restrict__ ei, const float* __restrict__ ew,
                       int* cur_f, int* csr_f_idx, float* csr_f_w,
                       int* cur_b, int* csr_b_idx, float* csr_b_w) {
    int e = blockIdx.x * blockDim.x + threadIdx.x;  // EE exactly
    int s = ei[e], t = ei[EE + e]; float w = ew[e];
    int pf = atomicAdd(&cur_f[t], 1); csr_f_idx[pf] = s; csr_f_w[pf] = w;
    int pb = atomicAdd(&cur_b[s], 1); csr_b_idx[pb] = t; csr_b_w[pb] = w;
}

// ---- MFMA GRU over T=12. Wave = 16 rows; G[16x96] = H[16x32] @ W[32x96] via
// 6 gate-tiles x 2 K-halves of mfma_f32_16x16x16_f16 (documented classic layout:
// A row=l&15, k=(l>>4)*4+e; D col=l&15 (gate j within tile), row=(l>>4)*4+reg).
// W staged in LDS in exactly the assumed fragment order, so any k-permutation
// error cancels between A and B. CB biases ride in as the MFMA C operand.
// h round-trips per step through a per-wave LDS tile: 8 ds_write_b16 ->
// lgkmcnt(0)+sched_barrier -> 2 ds_read_b64. Block = 4 independent waves.
__global__ __launch_bounds__(256) void k_gru(const float* __restrict__ x,
                      const float* __restrict__ CB, const float* __restrict__ Ag,
                      const float* __restrict__ w_hh, const float* __restrict__ b_hh,
                      __half* __restrict__ hout16) {
    __shared__ unsigned sW[1536];        // 12 frags x 64 lanes x 4 halves
    __shared__ __half  shh[4][16*40];    // per-wave h tile, row stride 40 halves (80B)
    __shared__ float   sx[64][12];
    int tid = threadIdx.x;
    int r0b = blockIdx.x * 64;           // 1250 blocks -> 80000 rows

    // stage W fragments: frag fi = tk*64+l (tk = gate_tile*2 + khalf); elem e <-> k
    for (int d = tid; d < 1536; d += 256) {
        int fi = d >> 1, epair = d & 1;
        int l = fi & 63, tk = fi >> 6;
        int gt = tk >> 1, kh = tk & 1;
        int gate = 16*gt + (l & 15);
        int k = kh*16 + ((l >> 4) << 2) + 2*epair;
        sW[d] = pkh2(w_hh[gate*32 + k], w_hh[gate*32 + k + 1]);
    }
    for (int i = tid; i < 64*12; i += 256) {
        int row = i / 12, t = i - row*12;
        int r = r0b + row; int b = r / NN, n = r - b*NN;
        sx[row][t] = x[((size_t)b*TT + t)*NN + n];
    }
    __syncthreads();

    const int wv = tid >> 6, l = tid & 63;
    const int c = l & 15, m = l >> 4;
    const int r0w = r0b + wv*16;

    // per-lane rows (D layout): rows 4m+q
    int bb[4], nn_[4];
    #pragma unroll
    for (int q = 0; q < 4; q++) {
        int r = r0w + 4*m + q;
        bb[q] = r / NN; nn_[q] = r - bb[q]*NN;
    }

    // bias preload (j = 16*t2 + c)
    float cNx[2][4];
    f32x4 crv[2], czv[2], cnv[2];
    float aRj[2], aZj[2], aNj[2], bn0c[2];
    #pragma unroll
    for (int t2 = 0; t2 < 2; t2++) {
        int j = 16*t2 + c;
        #pragma unroll
        for (int q = 0; q < 4; q++) {
            const float* cb = CB + (size_t)nn_[q]*96;
            crv[t2][q] = cb[j];
            czv[t2][q] = cb[32 + j];
            cNx[t2][q] = cb[64 + j];
        }
        bn0c[t2] = b_hh[64 + j];
        cnv[t2] = (f32x4){bn0c[t2], bn0c[t2], bn0c[t2], bn0c[t2]};
        aRj[t2] = Ag[j]; aZj[t2] = Ag[32 + j]; aNj[t2] = Ag[64 + j];
    }

    // W fragments LDS -> regs (frag i = gate_tile*2 + khalf)
    f16x4 bf[12];
    #pragma unroll
    for (int i = 0; i < 12; i++) {
        unsigned long long v = *(const unsigned long long*)(sW + (i*64 + l)*2);
        bf[i] = __builtin_bit_cast(f16x4, v);
    }

    __half* hb = shh[wv];
    float own[2][4];
    {   // t = 0: h = 0, no MFMA
        #pragma unroll
        for (int t2 = 0; t2 < 2; t2++)
        #pragma unroll
        for (int q = 0; q < 4; q++) {
            float xv = sx[wv*16 + 4*m + q][0];
            float rr = sigm(fmaf(xv, aRj[t2], crv[t2][q]));
            float zz = sigm(fmaf(xv, aZj[t2], czv[t2][q]));
            float nv = tanh_fast(fmaf(xv, aNj[t2], cNx[t2][q]) + rr * bn0c[t2]);
            own[t2][q] = (1.f - zz) * nv;
        }
    }
    #pragma unroll
    for (int t2 = 0; t2 < 2; t2++)
    #pragma unroll
    for (int q = 0; q < 4; q++)
        hb[(4*m + q)*40 + 16*t2 + c] = __float2half_rn(own[t2][q]);

    #pragma unroll 1
    for (int t = 1; t < TT; t++) {
        asm volatile("s_waitcnt lgkmcnt(0)" ::: "memory");
        __builtin_amdgcn_sched_barrier(0);
        // A fragments: lane reads h[row=c][k = kh*16 + m*4 + e]
        unsigned long long va0 = *(const unsigned long long*)(hb + c*40 + m*4);
        unsigned long long va1 = *(const unsigned long long*)(hb + c*40 + 16 + m*4);
        f16x4 a0 = __builtin_bit_cast(f16x4, va0);
        f16x4 a1 = __builtin_bit_cast(f16x4, va1);
        float xq[4];
        #pragma unroll
        for (int q = 0; q < 4; q++) xq[q] = sx[wv*16 + 4*m + q][t];

        f32x4 aR[2], aZ[2], aN[2];
        #pragma unroll
        for (int t2 = 0; t2 < 2; t2++) {
            aR[t2] = __builtin_amdgcn_mfma_f32_16x16x16f16(a0, bf[(t2    )*2    ], crv[t2], 0, 0, 0);
            aR[t2] = __builtin_amdgcn_mfma_f32_16x16x16f16(a1, bf[(t2    )*2 + 1], aR[t2], 0, 0, 0);
            aZ[t2] = __builtin_amdgcn_mfma_f32_16x16x16f16(a0, bf[(2 + t2)*2    ], czv[t2], 0, 0, 0);
            aZ[t2] = __builtin_amdgcn_mfma_f32_16x16x16f16(a1, bf[(2 + t2)*2 + 1], aZ[t2], 0, 0, 0);
            aN[t2] = __builtin_amdgcn_mfma_f32_16x16x16f16(a0, bf[(4 + t2)*2    ], cnv[t2], 0, 0, 0);
            aN[t2] = __builtin_amdgcn_mfma_f32_16x16x16f16(a1, bf[(4 + t2)*2 + 1], aN[t2], 0, 0, 0);
        }
        #pragma unroll
        for (int t2 = 0; t2 < 2; t2++)
        #pragma unroll
        for (int q = 0; q < 4; q++) {
            float rr = sigm(fmaf(xq[q], aRj[t2], aR[t2][q]));
            float zz = sigm(fmaf(xq[q], aZj[t2], aZ[t2][q]));
            float nv = tanh_fast(fmaf(xq[q], aNj[t2], cNx[t2][q]) + rr * aN[t2][q]);
            own[t2][q] = (1.f - zz) * nv + zz * own[t2][q];
        }
        if (t < TT-1) {
            #pragma unroll
            for (int t2 = 0; t2 < 2; t2++)
            #pragma unroll
            for (int q = 0; q < 4; q++)
                hb[(4*m + q)*40 + 16*t2 + c] = __float2half_rn(own[t2][q]);
        }
    }
    #pragma unroll
    for (int t2 = 0; t2 < 2; t2++)
    #pragma unroll
    for (int q = 0; q < 4; q++)
        hout16[((size_t)nn_[q]*BB + bb[q])*HH + 16*t2 + c] = __float2half(own[t2][q]);
}

// ---- diffusion hop: wave = (node, dir); normalization computed in-kernel:
// acc = (sum_e w[e] * x[idx[e]]) * rcp(sum_e w[e])
__global__ __launch_bounds__(256) void k_prop(
        const __half* __restrict__ xF, const __half* __restrict__ xB,
        __half* __restrict__ yF16, __half* __restrict__ yB16,
        const int* __restrict__ offF, const int* __restrict__ idxF, const float* __restrict__ wF,
        const int* __restrict__ offB, const int* __restrict__ idxB, const float* __restrict__ wB) {
    int wid = threadIdx.x >> 6;         // 0..3
    int l   = threadIdx.x & 63;
    int nd = blockIdx.x * 4 + wid;      // 5000 blocks -> 20000 = NN*2
    int n = nd >> 1, dir = nd & 1;
    const unsigned* xu = (const unsigned*)(dir ? xB : xF);
    const int* off = dir ? offB : offF;
    const int* idx = dir ? idxB : idxF;
    const float* w = dir ? wB : wF;

    int e0 = off[n], e1 = off[n+1];
    float a0 = 0.f, a1 = 0.f, a2 = 0.f, a3 = 0.f, ws = 0.f;
    int e = e0;
    for (; e + 8 <= e1; e += 8) {
        int   s0 = idx[e],   s1 = idx[e+1], s2 = idx[e+2], s3 = idx[e+3];
        int   s4 = idx[e+4], s5 = idx[e+5], s6 = idx[e+6], s7 = idx[e+7];
        float w0 = w[e],     w1 = w[e+1],   w2 = w[e+2],   w3 = w[e+3];
        float w4 = w[e+4],   w5 = w[e+5],   w6 = w[e+6],   w7 = w[e+7];
        uint2 u0 = *(const uint2*)(xu + ((size_t)s0 << 7) + 2*l);
        uint2 u1 = *(const uint2*)(xu + ((size_t)s1 << 7) + 2*l);
        uint2 u2 = *(const uint2*)(xu + ((size_t)s2 << 7) + 2*l);
        uint2 u3 = *(const uint2*)(xu + ((size_t)s3 << 7) + 2*l);
        uint2 u4 = *(const uint2*)(xu + ((size_t)s4 << 7) + 2*l);
        uint2 u5 = *(const uint2*)(xu + ((size_t)s5 << 7) + 2*l);
        uint2 u6 = *(const uint2*)(xu + ((size_t)s6 << 7) + 2*l);
        uint2 u7 = *(const uint2*)(xu + ((size_t)s7 << 7) + 2*l);
        ws += ((w0 + w1) + (w2 + w3)) + ((w4 + w5) + (w6 + w7));
        float2 f;
        f = uph2(u0.x); a0 = fmaf(w0, f.x, a0); a1 = fmaf(w0, f.y, a1);
        f = uph2(u0.y); a2 = fmaf(w0, f.x, a2); a3 = fmaf(w0, f.y, a3);
        f = uph2(u1.x); a0 = fmaf(w1, f.x, a0); a1 = fmaf(w1, f.y, a1);
        f = uph2(u1.y); a2 = fmaf(w1, f.x, a2); a3 = fmaf(w1, f.y, a3);
        f = uph2(u2.x); a0 = fmaf(w2, f.x, a0); a1 = fmaf(w2, f.y, a1);
        f = uph2(u2.y); a2 = fmaf(w2, f.x, a2); a3 = fmaf(w2, f.y, a3);
        f = uph2(u3.x); a0 = fmaf(w3, f.x, a0); a1 = fmaf(w3, f.y, a1);
        f = uph2(u3.y); a2 = fmaf(w3, f.x, a2); a3 = fmaf(w3, f.y, a3);
        f = uph2(u4.x); a0 = fmaf(w4, f.x, a0); a1 = fmaf(w4, f.y, a1);
        f = uph2(u4.y); a2 = fmaf(w4, f.x, a2); a3 = fmaf(w4, f.y, a3);
        f = uph2(u5.x); a0 = fmaf(w5, f.x, a0); a1 = fmaf(w5, f.y, a1);
        f = uph2(u5.y); a2 = fmaf(w5, f.x, a2); a3 = fmaf(w5, f.y, a3);
        f = uph2(u6.x); a0 = fmaf(w6, f.x, a0); a1 = fmaf(w6, f.y, a1);
        f = uph2(u6.y); a2 = fmaf(w6, f.x, a2); a3 = fmaf(w6, f.y, a3);
        f = uph2(u7.x); a0 = fmaf(w7, f.x, a0); a1 = fmaf(w7, f.y, a1);
        f = uph2(u7.y); a2 = fmaf(w7, f.x, a2); a3 = fmaf(w7, f.y, a3);
    }
    for (; e < e1; ++e) {
        int s0 = idx[e]; float w0 = w[e];
        uint2 u0 = *(const uint2*)(xu + ((size_t)s0 << 7) + 2*l);
        ws += w0;
        float2 f;
        f = uph2(u0.x); a0 = fmaf(w0, f.x, a0); a1 = fmaf(w0, f.y, a1);
        f = uph2(u0.y); a2 = fmaf(w0, f.x, a2); a3 = fmaf(w0, f.y, a3);
    }
    float inv = ws > 0.f ? __builtin_amdgcn_rcpf(ws) : 1.0f;
    a0 *= inv; a1 *= inv; a2 *= inv; a3 *= inv;
    unsigned* yh = (unsigned*)(dir ? yB16 : yF16);
    uint2 oh; oh.x = pkh2(a0, a1); oh.y = pkh2(a2, a3);
    *(uint2*)(yh + ((size_t)n << 7) + 2*l) = oh;
}

// ---- fused decoder (fp16 pieces): out[b,t,n] = b2[t] + sum piece_pi[n,b,c]*W2[pi*32+c,t]
__global__ __launch_bounds__(256) void k_dec(const __half* __restrict__ p0,
                     const __half* __restrict__ p1, const __half* __restrict__ p2,
                     const __half* __restrict__ p3, const __half* __restrict__ p4,
                     const float* __restrict__ W2, const float* __restrict__ b2,
                     float* __restrict__ out) {
    __shared__ float sW[1920];
    __shared__ float sb[12];
    int tid = threadIdx.x;
    for (int i = tid; i < 1920; i += 256) sW[i] = W2[i];
    if (tid < 12) sb[tid] = b2[tid];
    __syncthreads();
    int r = blockIdx.x * 256 + tid;
    if (r >= BB*NN) return;
    int b = r / NN, n = r - b*NN;
    size_t base = ((size_t)n * BB + b) * HH;
    float a[12];
    #pragma unroll
    for (int o = 0; o < 12; o++) a[o] = sb[o];
    const __half* ps[5] = {p0, p1, p2, p3, p4};
    #pragma unroll
    for (int pi = 0; pi < 5; pi++) {
        const uint4* pp = (const uint4*)(ps[pi] + base);
        #pragma unroll
        for (int q = 0; q < 4; q++) {
            uint4 v = pp[q];
            float2 f0 = uph2(v.x), f1 = uph2(v.y), f2 = uph2(v.z), f3 = uph2(v.w);
            float pv[8] = {f0.x, f0.y, f1.x, f1.y, f2.x, f2.y, f3.x, f3.y};
            #pragma unroll
            for (int k = 0; k < 8; k++) {
                const float* wrow = sW + (pi*32 + q*8 + k) * 12;
                #pragma unroll
                for (int o = 0; o < 12; o++) a[o] = fmaf(pv[k], wrow[o], a[o]);
            }
        }
    }
    #pragma unroll
    for (int t = 0; t < HOR; t++)
        out[((size_t)(b*HOR + t))*NN + n] = a[t];
}

extern "C" void kernel_launch(void* const* d_in, const int* in_sizes, int n_in,
                              void* d_out, int out_size, void* d_ws, size_t ws_size,
                              hipStream_t stream) {
    const float* x      = (const float*)d_in[0];
    const int*   ei     = (const int*)d_in[1];
    const float* ew     = (const float*)d_in[2];
    const float* enc_w  = (const float*)d_in[3];
    const float* enc_b  = (const float*)d_in[4];
    const float* nemb   = (const float*)d_in[5];
    const float* w_ih   = (const float*)d_in[6];
    const float* w_hh   = (const float*)d_in[7];
    const float* b_ih   = (const float*)d_in[8];
    const float* b_hh   = (const float*)d_in[9];
    const float* filt_w = (const float*)d_in[10];
    const float* filt_b = (const float*)d_in[11];
    const float* dec_w  = (const float*)d_in[12];
    const float* dec_b  = (const float*)d_in[13];
    float* out = (float*)d_out;

    char* p = (char*)d_ws;
    auto alloc = [&](size_t bytes) -> char* {
        char* q = p; p += (bytes + 255) & ~(size_t)255; return q;
    };
    // zero-region (single memset): cnt_f, cnt_b
    char* zero_base = p;
    int*   cnt_f = (int*)  alloc((size_t)NN*4);
    int*   cnt_b = (int*)  alloc((size_t)NN*4);
    size_t zero_bytes = (size_t)(p - zero_base);

    const size_t SROW = (size_t)BB*NN*HH;
    __half* h16    = (__half*)alloc(SROW*2);
    __half* a16    = (__half*)alloc(SROW*2);
    __half* b16    = (__half*)alloc(SROW*2);
    __half* c16    = (__half*)alloc(SROW*2);
    __half* d16    = (__half*)alloc(SROW*2);
    float* CB     = (float*)alloc((size_t)NN*96*4);
    float* A      = (float*)alloc(96*4);
    float* W2     = (float*)alloc(1920*4);
    float* b2     = (float*)alloc(12*4);
    int*   off_f  = (int*)  alloc((size_t)(NN+1)*4);
    int*   off_b  = (int*)  alloc((size_t)(NN+1)*4);
    int*   cur_f  = (int*)  alloc((size_t)NN*4);
    int*   cur_b  = (int*)  alloc((size_t)NN*4);
    int*   cfi    = (int*)  alloc((size_t)EE*4);
    float* cfw    = (float*)alloc((size_t)EE*4);
    int*   cbi    = (int*)  alloc((size_t)EE*4);
    float* cbw    = (float*)alloc((size_t)EE*4);

    hipMemsetAsync(zero_base, 0, zero_bytes, stream);

    k_cbhist<<<5001, 256, 0, stream>>>(nemb, enc_b, w_ih, b_ih, b_hh,
                                       enc_w, filt_w, filt_b, dec_w, dec_b,
                                       CB, A, W2, b2, ei, cnt_f, cnt_b);
    k_scan<<<2, 1024, 0, stream>>>(cnt_f, off_f, cur_f, cnt_b, off_b, cur_b);
    k_fill<<<EE/256, 256, 0, stream>>>(ei, ew, cur_f, cfi, cfw, cur_b, cbi, cbw);

    k_gru<<<1250, 256, 0, stream>>>(x, CB, A, w_hh, b_hh, h16);

    k_prop<<<5000, 256, 0, stream>>>(h16, h16, a16, c16,
                                     off_f, cfi, cfw, off_b, cbi, cbw);
    k_prop<<<5000, 256, 0, stream>>>(a16, c16, b16, d16,
                                     off_f, cfi, cfw, off_b, cbi, cbw);

    k_dec<<<(BB*NN + 255)/256, 256, 0, stream>>>(h16, a16, b16, c16, d16, W2, b2, out);
}

// Round 11
// 221.480 us; speedup vs baseline: 10.9751x; 1.0461x over previous
//
#include <hip/hip_runtime.h>
#include <hip/hip_fp16.h>

#define BB 8
#define TT 12
#define NN 10000
#define HH 32
#define EE 320000
#define HOR 12
#define NCB 157   // ceil(NN/64) CB blocks in k_cbhist

static __device__ __forceinline__ float sigm(float x) {
    return __builtin_amdgcn_rcpf(1.0f + __expf(-x));
}
static __device__ __forceinline__ float tanh_fast(float x) {
    return 1.0f - 2.0f * __builtin_amdgcn_rcpf(1.0f + __expf(2.0f * x));
}
static __device__ __forceinline__ float2 uph2(unsigned u) {
    __half2 h = *(__half2*)&u;
    return __half22float2(h);
}
static __device__ __forceinline__ unsigned pkh2(float a, float b) {
    __half2 h = __floats2half2_rn(a, b);
    return *(unsigned*)&h;
}

typedef _Float16 f16x4 __attribute__((ext_vector_type(4)));
typedef float    f32x4 __attribute__((ext_vector_type(4)));

// ---- fused: CB GEMM-style (blocks 0..156), tiny prep (157), edge count histogram (158..1407)
__global__ void k_cbhist(const float* __restrict__ node_emb, const float* __restrict__ enc_b,
                     const float* __restrict__ w_ih, const float* __restrict__ b_ih,
                     const float* __restrict__ b_hh,
                     const float* __restrict__ enc_w, const float* __restrict__ filt_w,
                     const float* __restrict__ filt_b, const float* __restrict__ dec_w,
                     const float* __restrict__ dec_b,
                     float* __restrict__ CB, float* __restrict__ A,
                     float* __restrict__ W2, float* __restrict__ b2,
                     const int* __restrict__ ei,
                     int* cnt_f, int* cnt_b) {
    __shared__ float sw[96*36];    // w_ih, stride-36 (float4-aligned, bank-spread)
    __shared__ float semb[64*36];  // enc_b + node_emb rows
    __shared__ float sbias[96];    // b_ih + b_hh(r,z)
    int bid = blockIdx.x;
    int tid = threadIdx.x;
    if (bid < NCB) {               // CB: 64 nodes/block, LDS-staged, coalesced
        int n0 = bid * 64;
        for (int i = tid; i < 96*32; i += 256) {
            int g = i >> 5, h = i & 31;
            sw[g*36 + h] = w_ih[i];
        }
        for (int i = tid; i < 64*32; i += 256) {
            int row = i >> 5, h = i & 31;
            int n = n0 + row; if (n >= NN) n = NN-1;
            semb[row*36 + h] = enc_b[h] + node_emb[(size_t)n*32 + h];
        }
        if (tid < 96) sbias[tid] = b_ih[tid] + (tid < 64 ? b_hh[tid] : 0.f);
        __syncthreads();
        #pragma unroll 1
        for (int i = 0; i < 24; i++) {
            int o = i*256 + tid;           // 0..6143, flat -> coalesced write
            int row = o / 96, g = o - row*96;
            int n = n0 + row;
            if (n < NN) {
                float s = sbias[g];
                const float4* ev = (const float4*)(semb + row*36);
                const float4* wv = (const float4*)(sw + g*36);
                #pragma unroll
                for (int q = 0; q < 8; q++) {
                    float4 e = ev[q], w = wv[q];
                    s = fmaf(e.x, w.x, s); s = fmaf(e.y, w.y, s);
                    s = fmaf(e.z, w.z, s); s = fmaf(e.w, w.w, s);
                }
                CB[(size_t)n*96 + g] = s;
            }
        }
    } else if (bid == NCB) {       // prep
        for (int i = tid; i < 96 + 160*12 + 12; i += blockDim.x) {
            if (i < 96) {
                float s = 0.f;
                for (int h = 0; h < HH; h++) s += enc_w[h] * w_ih[i*HH + h];
                A[i] = s;
            } else if (i < 96 + 1920) {
                int j = i - 96; int c = j / 12, o = j % 12;
                float s = 0.f;
                for (int h = 0; h < HH; h++) s += filt_w[c*HH + h] * dec_w[h*12 + o];
                W2[j] = s;
            } else {
                int o = i - 2016;
                float s = dec_b[o];
                for (int h = 0; h < HH; h++) s += filt_b[h] * dec_w[h*12 + o];
                b2[o] = s;
            }
        }
    } else {                       // count histogram (normalization lives in k_prop)
        int e = (bid - NCB - 1) * 256 + tid;
        int s = ei[e], t = ei[EE + e];
        atomicAdd(&cnt_f[t], 1);
        atomicAdd(&cnt_b[s], 1);
    }
}

// ---- single-block exclusive scan (2 blocks: fwd / bwd)
__global__ void k_scan(const int* __restrict__ cnt_f, int* off_f, int* cur_f,
                       const int* __restrict__ cnt_b, int* off_b, int* cur_b) {
    const int* cnt; int* off; int* cur;
    if (blockIdx.x == 0) { cnt = cnt_f; off = off_f; cur = cur_f; }
    else                 { cnt = cnt_b; off = off_b; cur = cur_b; }
    __shared__ int part[1024];
    int t = threadIdx.x;
    const int CH = (NN + 1023) / 1024;  // 10
    int beg = t * CH, end = min(beg + CH, NN);
    int s = 0;
    for (int i = beg; i < end; i++) s += cnt[i];
    part[t] = s;
    __syncthreads();
    for (int d = 1; d < 1024; d <<= 1) {
        int add = (t >= d) ? part[t - d] : 0;
        __syncthreads();
        part[t] += add;
        __syncthreads();
    }
    int run = part[t] - s;  // exclusive base
    for (int i = beg; i < end; i++) {
        off[i] = run; cur[i] = run; run += cnt[i];
    }
    if (t == 1023) off[NN] = part[1023];
}

// ---- scatter edges into CSR buckets (raw weights; prop normalizes)
__global__ void k_fill(const int* __restrict__ ei, const float* __restrict__ ew,
                       int* cur_f, int* csr_f_idx, float* csr_f_w,
                       int* cur_b, int* csr_b_idx, float* csr_b_w) {
    int e = blockIdx.x * blockDim.x + threadIdx.x;  // EE exactly
    int s = ei[e], t = ei[EE + e]; float w = ew[e];
    int pf = atomicAdd(&cur_f[t], 1); csr_f_idx[pf] = s; csr_f_w[pf] = w;
    int pb = atomicAdd(&cur_b[s], 1); csr_b_idx[pb] = t; csr_b_w[pb] = w;
}

// ---- MFMA GRU over T=12 (unchanged from R10: verified correct & fast)
__global__ __launch_bounds__(256) void k_gru(const float* __restrict__ x,
                      const float* __restrict__ CB, const float* __restrict__ Ag,
                      const float* __restrict__ w_hh, const float* __restrict__ b_hh,
                      __half* __restrict__ hout16) {
    __shared__ unsigned sW[1536];        // 12 frags x 64 lanes x 4 halves
    __shared__ __half  shh[4][16*40];    // per-wave h tile, row stride 40 halves
    __shared__ float   sx[64][12];
    int tid = threadIdx.x;
    int r0b = blockIdx.x * 64;           // 1250 blocks -> 80000 rows

    for (int d = tid; d < 1536; d += 256) {
        int fi = d >> 1, epair = d & 1;
        int l = fi & 63, tk = fi >> 6;
        int gt = tk >> 1, kh = tk & 1;
        int gate = 16*gt + (l & 15);
        int k = kh*16 + ((l >> 4) << 2) + 2*epair;
        sW[d] = pkh2(w_hh[gate*32 + k], w_hh[gate*32 + k + 1]);
    }
    for (int i = tid; i < 64*12; i += 256) {
        int row = i / 12, t = i - row*12;
        int r = r0b + row; int b = r / NN, n = r - b*NN;
        sx[row][t] = x[((size_t)b*TT + t)*NN + n];
    }
    __syncthreads();

    const int wv = tid >> 6, l = tid & 63;
    const int c = l & 15, m = l >> 4;
    const int r0w = r0b + wv*16;

    int bb[4], nn_[4];
    #pragma unroll
    for (int q = 0; q < 4; q++) {
        int r = r0w + 4*m + q;
        bb[q] = r / NN; nn_[q] = r - bb[q]*NN;
    }

    float cNx[2][4];
    f32x4 crv[2], czv[2], cnv[2];
    float aRj[2], aZj[2], aNj[2], bn0c[2];
    #pragma unroll
    for (int t2 = 0; t2 < 2; t2++) {
        int j = 16*t2 + c;
        #pragma unroll
        for (int q = 0; q < 4; q++) {
            const float* cb = CB + (size_t)nn_[q]*96;
            crv[t2][q] = cb[j];
            czv[t2][q] = cb[32 + j];
            cNx[t2][q] = cb[64 + j];
        }
        bn0c[t2] = b_hh[64 + j];
        cnv[t2] = (f32x4){bn0c[t2], bn0c[t2], bn0c[t2], bn0c[t2]};
        aRj[t2] = Ag[j]; aZj[t2] = Ag[32 + j]; aNj[t2] = Ag[64 + j];
    }

    f16x4 bf[12];
    #pragma unroll
    for (int i = 0; i < 12; i++) {
        unsigned long long v = *(const unsigned long long*)(sW + (i*64 + l)*2);
        bf[i] = __builtin_bit_cast(f16x4, v);
    }

    __half* hb = shh[wv];
    float own[2][4];
    {
        #pragma unroll
        for (int t2 = 0; t2 < 2; t2++)
        #pragma unroll
        for (int q = 0; q < 4; q++) {
            float xv = sx[wv*16 + 4*m + q][0];
            float rr = sigm(fmaf(xv, aRj[t2], crv[t2][q]));
            float zz = sigm(fmaf(xv, aZj[t2], czv[t2][q]));
            float nv = tanh_fast(fmaf(xv, aNj[t2], cNx[t2][q]) + rr * bn0c[t2]);
            own[t2][q] = (1.f - zz) * nv;
        }
    }
    #pragma unroll
    for (int t2 = 0; t2 < 2; t2++)
    #pragma unroll
    for (int q = 0; q < 4; q++)
        hb[(4*m + q)*40 + 16*t2 + c] = __float2half_rn(own[t2][q]);

    #pragma unroll 1
    for (int t = 1; t < TT; t++) {
        asm volatile("s_waitcnt lgkmcnt(0)" ::: "memory");
        __builtin_amdgcn_sched_barrier(0);
        unsigned long long va0 = *(const unsigned long long*)(hb + c*40 + m*4);
        unsigned long long va1 = *(const unsigned long long*)(hb + c*40 + 16 + m*4);
        f16x4 a0 = __builtin_bit_cast(f16x4, va0);
        f16x4 a1 = __builtin_bit_cast(f16x4, va1);
        float xq[4];
        #pragma unroll
        for (int q = 0; q < 4; q++) xq[q] = sx[wv*16 + 4*m + q][t];

        f32x4 aR[2], aZ[2], aN[2];
        #pragma unroll
        for (int t2 = 0; t2 < 2; t2++) {
            aR[t2] = __builtin_amdgcn_mfma_f32_16x16x16f16(a0, bf[(t2    )*2    ], crv[t2], 0, 0, 0);
            aR[t2] = __builtin_amdgcn_mfma_f32_16x16x16f16(a1, bf[(t2    )*2 + 1], aR[t2], 0, 0, 0);
            aZ[t2] = __builtin_amdgcn_mfma_f32_16x16x16f16(a0, bf[(2 + t2)*2    ], czv[t2], 0, 0, 0);
            aZ[t2] = __builtin_amdgcn_mfma_f32_16x16x16f16(a1, bf[(2 + t2)*2 + 1], aZ[t2], 0, 0, 0);
            aN[t2] = __builtin_amdgcn_mfma_f32_16x16x16f16(a0, bf[(4 + t2)*2    ], cnv[t2], 0, 0, 0);
            aN[t2] = __builtin_amdgcn_mfma_f32_16x16x16f16(a1, bf[(4 + t2)*2 + 1], aN[t2], 0, 0, 0);
        }
        #pragma unroll
        for (int t2 = 0; t2 < 2; t2++)
        #pragma unroll
        for (int q = 0; q < 4; q++) {
            float rr = sigm(fmaf(xq[q], aRj[t2], aR[t2][q]));
            float zz = sigm(fmaf(xq[q], aZj[t2], aZ[t2][q]));
            float nv = tanh_fast(fmaf(xq[q], aNj[t2], cNx[t2][q]) + rr * aN[t2][q]);
            own[t2][q] = (1.f - zz) * nv + zz * own[t2][q];
        }
        if (t < TT-1) {
            #pragma unroll
            for (int t2 = 0; t2 < 2; t2++)
            #pragma unroll
            for (int q = 0; q < 4; q++)
                hb[(4*m + q)*40 + 16*t2 + c] = __float2half_rn(own[t2][q]);
        }
    }
    #pragma unroll
    for (int t2 = 0; t2 < 2; t2++)
    #pragma unroll
    for (int q = 0; q < 4; q++)
        hout16[((size_t)nn_[q]*BB + bb[q])*HH + 16*t2 + c] = __float2half(own[t2][q]);
}

// ---- diffusion hop (unchanged): wave = (node, dir), in-kernel normalization
__global__ __launch_bounds__(256) void k_prop(
        const __half* __restrict__ xF, const __half* __restrict__ xB,
        __half* __restrict__ yF16, __half* __restrict__ yB16,
        const int* __restrict__ offF, const int* __restrict__ idxF, const float* __restrict__ wF,
        const int* __restrict__ offB, const int* __restrict__ idxB, const float* __restrict__ wB) {
    int wid = threadIdx.x >> 6;         // 0..3
    int l   = threadIdx.x & 63;
    int nd = blockIdx.x * 4 + wid;      // 5000 blocks -> 20000 = NN*2
    int n = nd >> 1, dir = nd & 1;
    const unsigned* xu = (const unsigned*)(dir ? xB : xF);
    const int* off = dir ? offB : offF;
    const int* idx = dir ? idxB : idxF;
    const float* w = dir ? wB : wF;

    int e0 = off[n], e1 = off[n+1];
    float a0 = 0.f, a1 = 0.f, a2 = 0.f, a3 = 0.f, ws = 0.f;
    int e = e0;
    for (; e + 8 <= e1; e += 8) {
        int   s0 = idx[e],   s1 = idx[e+1], s2 = idx[e+2], s3 = idx[e+3];
        int   s4 = idx[e+4], s5 = idx[e+5], s6 = idx[e+6], s7 = idx[e+7];
        float w0 = w[e],     w1 = w[e+1],   w2 = w[e+2],   w3 = w[e+3];
        float w4 = w[e+4],   w5 = w[e+5],   w6 = w[e+6],   w7 = w[e+7];
        uint2 u0 = *(const uint2*)(xu + ((size_t)s0 << 7) + 2*l);
        uint2 u1 = *(const uint2*)(xu + ((size_t)s1 << 7) + 2*l);
        uint2 u2 = *(const uint2*)(xu + ((size_t)s2 << 7) + 2*l);
        uint2 u3 = *(const uint2*)(xu + ((size_t)s3 << 7) + 2*l);
        uint2 u4 = *(const uint2*)(xu + ((size_t)s4 << 7) + 2*l);
        uint2 u5 = *(const uint2*)(xu + ((size_t)s5 << 7) + 2*l);
        uint2 u6 = *(const uint2*)(xu + ((size_t)s6 << 7) + 2*l);
        uint2 u7 = *(const uint2*)(xu + ((size_t)s7 << 7) + 2*l);
        ws += ((w0 + w1) + (w2 + w3)) + ((w4 + w5) + (w6 + w7));
        float2 f;
        f = uph2(u0.x); a0 = fmaf(w0, f.x, a0); a1 = fmaf(w0, f.y, a1);
        f = uph2(u0.y); a2 = fmaf(w0, f.x, a2); a3 = fmaf(w0, f.y, a3);
        f = uph2(u1.x); a0 = fmaf(w1, f.x, a0); a1 = fmaf(w1, f.y, a1);
        f = uph2(u1.y); a2 = fmaf(w1, f.x, a2); a3 = fmaf(w1, f.y, a3);
        f = uph2(u2.x); a0 = fmaf(w2, f.x, a0); a1 = fmaf(w2, f.y, a1);
        f = uph2(u2.y); a2 = fmaf(w2, f.x, a2); a3 = fmaf(w2, f.y, a3);
        f = uph2(u3.x); a0 = fmaf(w3, f.x, a0); a1 = fmaf(w3, f.y, a1);
        f = uph2(u3.y); a2 = fmaf(w3, f.x, a2); a3 = fmaf(w3, f.y, a3);
        f = uph2(u4.x); a0 = fmaf(w4, f.x, a0); a1 = fmaf(w4, f.y, a1);
        f = uph2(u4.y); a2 = fmaf(w4, f.x, a2); a3 = fmaf(w4, f.y, a3);
        f = uph2(u5.x); a0 = fmaf(w5, f.x, a0); a1 = fmaf(w5, f.y, a1);
        f = uph2(u5.y); a2 = fmaf(w5, f.x, a2); a3 = fmaf(w5, f.y, a3);
        f = uph2(u6.x); a0 = fmaf(w6, f.x, a0); a1 = fmaf(w6, f.y, a1);
        f = uph2(u6.y); a2 = fmaf(w6, f.x, a2); a3 = fmaf(w6, f.y, a3);
        f = uph2(u7.x); a0 = fmaf(w7, f.x, a0); a1 = fmaf(w7, f.y, a1);
        f = uph2(u7.y); a2 = fmaf(w7, f.x, a2); a3 = fmaf(w7, f.y, a3);
    }
    for (; e < e1; ++e) {
        int s0 = idx[e]; float w0 = w[e];
        uint2 u0 = *(const uint2*)(xu + ((size_t)s0 << 7) + 2*l);
        ws += w0;
        float2 f;
        f = uph2(u0.x); a0 = fmaf(w0, f.x, a0); a1 = fmaf(w0, f.y, a1);
        f = uph2(u0.y); a2 = fmaf(w0, f.x, a2); a3 = fmaf(w0, f.y, a3);
    }
    float inv = ws > 0.f ? __builtin_amdgcn_rcpf(ws) : 1.0f;
    a0 *= inv; a1 *= inv; a2 *= inv; a3 *= inv;
    unsigned* yh = (unsigned*)(dir ? yB16 : yF16);
    uint2 oh; oh.x = pkh2(a0, a1); oh.y = pkh2(a2, a3);
    *(uint2*)(yh + ((size_t)n << 7) + 2*l) = oh;
}

// ---- fused decoder, 2-way piece split: 625 blocks x (128 rows x 2 halves).
// half 0: bias + pieces 0-2 (12 uint4 batch-loaded); half 1: pieces 3-4 -> LDS.
// Waves 1250 -> 2500; loads batched up-front for in-flight depth.
__global__ __launch_bounds__(256) void k_dec(const __half* __restrict__ p0,
                     const __half* __restrict__ p1, const __half* __restrict__ p2,
                     const __half* __restrict__ p3, const __half* __restrict__ p4,
                     const float* __restrict__ W2, const float* __restrict__ b2,
                     float* __restrict__ out) {
    __shared__ float sW[1920];
    __shared__ float sb[12];
    __shared__ float part[128][13];
    int tid = threadIdx.x;
    for (int i = tid; i < 1920; i += 256) sW[i] = W2[i];
    if (tid < 12) sb[tid] = b2[tid];
    __syncthreads();
    int lr = tid & 127, half = tid >> 7;
    int r = blockIdx.x * 128 + lr;      // 625 blocks exactly
    int b = r / NN, n = r - b*NN;
    size_t base = ((size_t)n * BB + b) * HH;
    float a[12];
    if (half == 0) {
        uint4 v[12];
        {
            const uint4* q0 = (const uint4*)(p0 + base);
            const uint4* q1 = (const uint4*)(p1 + base);
            const uint4* q2 = (const uint4*)(p2 + base);
            #pragma unroll
            for (int q = 0; q < 4; q++) { v[q] = q0[q]; v[4+q] = q1[q]; v[8+q] = q2[q]; }
        }
        #pragma unroll
        for (int o = 0; o < 12; o++) a[o] = sb[o];
        #pragma unroll
        for (int pi = 0; pi < 3; pi++)
        #pragma unroll
        for (int q = 0; q < 4; q++) {
            uint4 vv = v[pi*4 + q];
            float2 f0 = uph2(vv.x), f1 = uph2(vv.y), f2 = uph2(vv.z), f3 = uph2(vv.w);
            float pv[8] = {f0.x, f0.y, f1.x, f1.y, f2.x, f2.y, f3.x, f3.y};
            #pragma unroll
            for (int k = 0; k < 8; k++) {
                const float* wrow = sW + (pi*32 + q*8 + k) * 12;
                #pragma unroll
                for (int o = 0; o < 12; o++) a[o] = fmaf(pv[k], wrow[o], a[o]);
            }
        }
    } else {
        uint4 v[8];
        {
            const uint4* q3 = (const uint4*)(p3 + base);
            const uint4* q4 = (const uint4*)(p4 + base);
            #pragma unroll
            for (int q = 0; q < 4; q++) { v[q] = q3[q]; v[4+q] = q4[q]; }
        }
        #pragma unroll
        for (int o = 0; o < 12; o++) a[o] = 0.f;
        #pragma unroll
        for (int pi = 0; pi < 2; pi++)
        #pragma unroll
        for (int q = 0; q < 4; q++) {
            uint4 vv = v[pi*4 + q];
            float2 f0 = uph2(vv.x), f1 = uph2(vv.y), f2 = uph2(vv.z), f3 = uph2(vv.w);
            float pv[8] = {f0.x, f0.y, f1.x, f1.y, f2.x, f2.y, f3.x, f3.y};
            #pragma unroll
            for (int k = 0; k < 8; k++) {
                const float* wrow = sW + ((pi+3)*32 + q*8 + k) * 12;
                #pragma unroll
                for (int o = 0; o < 12; o++) a[o] = fmaf(pv[k], wrow[o], a[o]);
            }
        }
        #pragma unroll
        for (int o = 0; o < 12; o++) part[lr][o] = a[o];
    }
    __syncthreads();
    if (half == 0) {
        #pragma unroll
        for (int t = 0; t < HOR; t++)
            out[((size_t)(b*HOR + t))*NN + n] = a[t] + part[lr][t];
    }
}

extern "C" void kernel_launch(void* const* d_in, const int* in_sizes, int n_in,
                              void* d_out, int out_size, void* d_ws, size_t ws_size,
                              hipStream_t stream) {
    const float* x      = (const float*)d_in[0];
    const int*   ei     = (const int*)d_in[1];
    const float* ew     = (const float*)d_in[2];
    const float* enc_w  = (const float*)d_in[3];
    const float* enc_b  = (const float*)d_in[4];
    const float* nemb   = (const float*)d_in[5];
    const float* w_ih   = (const float*)d_in[6];
    const float* w_hh   = (const float*)d_in[7];
    const float* b_ih   = (const float*)d_in[8];
    const float* b_hh   = (const float*)d_in[9];
    const float* filt_w = (const float*)d_in[10];
    const float* filt_b = (const float*)d_in[11];
    const float* dec_w  = (const float*)d_in[12];
    const float* dec_b  = (const float*)d_in[13];
    float* out = (float*)d_out;

    char* p = (char*)d_ws;
    auto alloc = [&](size_t bytes) -> char* {
        char* q = p; p += (bytes + 255) & ~(size_t)255; return q;
    };
    // zero-region (single memset): cnt_f, cnt_b
    char* zero_base = p;
    int*   cnt_f = (int*)  alloc((size_t)NN*4);
    int*   cnt_b = (int*)  alloc((size_t)NN*4);
    size_t zero_bytes = (size_t)(p - zero_base);

    const size_t SROW = (size_t)BB*NN*HH;
    __half* h16    = (__half*)alloc(SROW*2);
    __half* a16    = (__half*)alloc(SROW*2);
    __half* b16    = (__half*)alloc(SROW*2);
    __half* c16    = (__half*)alloc(SROW*2);
    __half* d16    = (__half*)alloc(SROW*2);
    float* CB     = (float*)alloc((size_t)NN*96*4);
    float* A      = (float*)alloc(96*4);
    float* W2     = (float*)alloc(1920*4);
    float* b2     = (float*)alloc(12*4);
    int*   off_f  = (int*)  alloc((size_t)(NN+1)*4);
    int*   off_b  = (int*)  alloc((size_t)(NN+1)*4);
    int*   cur_f  = (int*)  alloc((size_t)NN*4);
    int*   cur_b  = (int*)  alloc((size_t)NN*4);
    int*   cfi    = (int*)  alloc((size_t)EE*4);
    float* cfw    = (float*)alloc((size_t)EE*4);
    int*   cbi    = (int*)  alloc((size_t)EE*4);
    float* cbw    = (float*)alloc((size_t)EE*4);

    hipMemsetAsync(zero_base, 0, zero_bytes, stream);

    k_cbhist<<<NCB + 1 + EE/256, 256, 0, stream>>>(nemb, enc_b, w_ih, b_ih, b_hh,
                                       enc_w, filt_w, filt_b, dec_w, dec_b,
                                       CB, A, W2, b2, ei, cnt_f, cnt_b);
    k_scan<<<2, 1024, 0, stream>>>(cnt_f, off_f, cur_f, cnt_b, off_b, cur_b);
    k_fill<<<EE/256, 256, 0, stream>>>(ei, ew, cur_f, cfi, cfw, cur_b, cbi, cbw);

    k_gru<<<1250, 256, 0, stream>>>(x, CB, A, w_hh, b_hh, h16);

    k_prop<<<5000, 256, 0, stream>>>(h16, h16, a16, c16,
                                     off_f, cfi, cfw, off_b, cbi, cbw);
    k_prop<<<5000, 256, 0, stream>>>(a16, c16, b16, d16,
                                     off_f, cfi, cfw, off_b, cbi, cbw);

    k_dec<<<625, 256, 0, stream>>>(h16, a16, b16, c16, d16, W2, b2, out);
}